// Round 5
// baseline (3916.764 us; speedup 1.0000x reference)
//
#include <hip/hip_runtime.h>
#include <hip/hip_bf16.h>
#include <cstdio>
#include <cstdint>

typedef __hip_bfloat16 bf16;

struct __align__(8) bf16x4 { bf16 x,y,z,w; };

static __device__ __forceinline__ float b2f(bf16 v){ return __bfloat162float(v); }
static __device__ __forceinline__ bf16  f2b(float v){ return __float2bfloat16(v); }
static __device__ __forceinline__ void  stf(float* p, float v){ *p = v; }
static __device__ __forceinline__ void  stf(bf16*  p, float v){ *p = f2b(v); }

// ---------------- graph prep ----------------

__global__ void k_cast(const float* __restrict__ x, bf16* __restrict__ xb, int n4){
  int i = blockIdx.x*256 + threadIdx.x;
  if(i<n4){
    float4 v = reinterpret_cast<const float4*>(x)[i];
    bf16x4 o{f2b(v.x),f2b(v.y),f2b(v.z),f2b(v.w)};
    reinterpret_cast<bf16x4*>(xb)[i] = o;
  }
}

__global__ void k_count(const int* __restrict__ dst, int* __restrict__ deg, int E){
  int e = blockIdx.x*256 + threadIdx.x;
  if(e<E) atomicAdd(&deg[dst[e]], 1);
}

__global__ void k_scan1(const int* __restrict__ deg, int* __restrict__ rp1, int* __restrict__ bsums, int N){
  __shared__ int s[256];
  int i = blockIdx.x*256 + threadIdx.x;
  int v = (i<N)? deg[i] : 0;
  s[threadIdx.x]=v; __syncthreads();
  for(int off=1; off<256; off<<=1){
    int t = (threadIdx.x>=off)? s[threadIdx.x-off] : 0;
    __syncthreads();
    s[threadIdx.x]+=t;
    __syncthreads();
  }
  if(i<N) rp1[i]=s[threadIdx.x];
  if(threadIdx.x==255) bsums[blockIdx.x]=s[255];
}

__global__ void k_scan2(const int* __restrict__ bsums, int* __restrict__ boffs, int NB){
  __shared__ int s[512];
  int x=threadIdx.x;
  int v = (x<NB)? bsums[x] : 0;
  s[x]=v; __syncthreads();
  for(int off=1; off<512; off<<=1){
    int t=(x>=off)? s[x-off]:0; __syncthreads();
    s[x]+=t; __syncthreads();
  }
  if(x<NB) boffs[x]=s[x]-v;  // exclusive prefix
}

__global__ void k_scan3(int* __restrict__ row_ptr, const int* __restrict__ boffs,
                        const int* __restrict__ deg, float* __restrict__ dis, int N){
  int i = blockIdx.x*256+threadIdx.x;
  if(i<N){
    row_ptr[i+1] += boffs[blockIdx.x];
    int d = deg[i];
    dis[i] = (d>0)? rsqrtf((float)d) : 0.f;
    if(i==0) row_ptr[0]=0;
  }
}

// CSR fill: packed {src, w} per edge -> ONE 8B scatter, and k_prop gets the
// weight as part of the same coalesced 8B load (round-4 lesson: a dependent
// dis[src] gather in the prop inner loop costs ~2x; keep weight independent).
__global__ void k_fill(const int* __restrict__ src, const int* __restrict__ dst, const float* __restrict__ dis,
                       const int* __restrict__ row_ptr, int* __restrict__ cursor,
                       int2* __restrict__ csr_ew, int E){
  int e = blockIdx.x*256+threadIdx.x;
  if(e<E){
    int d = dst[e], s = src[e];
    int pos = row_ptr[d] + atomicAdd(&cursor[d], 1);
    float w = dis[s]*dis[d];
    csr_ew[pos] = make_int2(s, __float_as_int(w));
  }
}

// ---------------- dense GEMM: C[Mx64] = A[MxK] @ W[Kx64] ----------------
// A bf16 (vec4 staged), W f32 (float4 staged); f32 accumulate; out f32 or bf16.
// sAT transposed [k][row] so inner loop reads are aligned ds_read_b128.

template<int K, bool BOUT>
__global__ __launch_bounds__(256,2) void k_gemm(const bf16* __restrict__ A, const float* __restrict__ W,
                                                float* __restrict__ Cf, bf16* __restrict__ Cb, int M){
  __shared__ float sAT[64][68];
  __shared__ float sW[64][64];
  const int t = threadIdx.x;
  const int m0 = blockIdx.x*64;
  const int tr = t>>4, tc = t&15;
  float acc[4][4] = {};
  for(int kc=0; kc<K/64; ++kc){
    #pragma unroll
    for(int it=0; it<4; ++it){
      int gli = t + it*256;       // vec4 index, 16 per row
      int r = gli>>4, c4 = (gli&15)*4;
      int m = m0 + r;
      float v0=0,v1=0,v2=0,v3=0;
      if(m < M){
        bf16x4 u = *reinterpret_cast<const bf16x4*>(&A[(size_t)m*K + kc*64 + c4]);
        v0=b2f(u.x); v1=b2f(u.y); v2=b2f(u.z); v3=b2f(u.w);
      }
      sAT[c4+0][r]=v0; sAT[c4+1][r]=v1; sAT[c4+2][r]=v2; sAT[c4+3][r]=v3;
    }
    #pragma unroll
    for(int it=0; it<4; ++it){
      int gli = t + it*256;
      int r = gli>>4, c4 = (gli&15)*4;
      float4 wv = *reinterpret_cast<const float4*>(&W[(size_t)(kc*64+r)*64 + c4]);
      *reinterpret_cast<float4*>(&sW[r][c4]) = wv;
    }
    __syncthreads();
    #pragma unroll 8
    for(int k=0;k<64;++k){
      const float4 av = *reinterpret_cast<const float4*>(&sAT[k][tr*4]);
      const float4 wv = *reinterpret_cast<const float4*>(&sW[k][tc*4]);
      acc[0][0]+=av.x*wv.x; acc[0][1]+=av.x*wv.y; acc[0][2]+=av.x*wv.z; acc[0][3]+=av.x*wv.w;
      acc[1][0]+=av.y*wv.x; acc[1][1]+=av.y*wv.y; acc[1][2]+=av.y*wv.z; acc[1][3]+=av.y*wv.w;
      acc[2][0]+=av.z*wv.x; acc[2][1]+=av.z*wv.y; acc[2][2]+=av.z*wv.z; acc[2][3]+=av.z*wv.w;
      acc[3][0]+=av.w*wv.x; acc[3][1]+=av.w*wv.y; acc[3][2]+=av.w*wv.z; acc[3][3]+=av.w*wv.w;
    }
    __syncthreads();
  }
  #pragma unroll
  for(int i=0;i<4;++i){
    int m = m0 + tr*4 + i;
    if(m<M){
      #pragma unroll
      for(int j=0;j<4;++j){
        int c = tc*4+j;
        if(BOUT) Cb[(size_t)m*64+c] = f2b(acc[i][j]);
        else     Cf[(size_t)m*64+c] = acc[i][j];
      }
    }
  }
}

// mix GEMM: A = [h(64) | xb(128)] bf16 (M x 192), W = [Wmix0 | Wmix1] (192 x (32+32))
// out: cols 0..31 -> Z0 (f32), cols 32..63 -> Z1 (bf16)
__global__ __launch_bounds__(256,2) void k_gemm_mix(const bf16* __restrict__ h, const bf16* __restrict__ xb,
     const float* __restrict__ Wmix, float* __restrict__ Z0, bf16* __restrict__ Z1, int M){
  __shared__ float sAT[64][68];
  __shared__ float sW[64][64];
  const int t=threadIdx.x, m0=blockIdx.x*64, tr=t>>4, tc=t&15;
  float acc[4][4]={};
  for(int kc=0;kc<3;++kc){
    #pragma unroll
    for(int it=0; it<4; ++it){
      int gli = t + it*256;
      int r = gli>>4, c4 = (gli&15)*4;
      int m = m0 + r;
      float v0=0,v1=0,v2=0,v3=0;
      if(m < M){
        bf16x4 u = (kc==0) ? *reinterpret_cast<const bf16x4*>(&h[(size_t)m*64 + c4])
                           : *reinterpret_cast<const bf16x4*>(&xb[(size_t)m*128 + (kc-1)*64 + c4]);
        v0=b2f(u.x); v1=b2f(u.y); v2=b2f(u.z); v3=b2f(u.w);
      }
      sAT[c4+0][r]=v0; sAT[c4+1][r]=v1; sAT[c4+2][r]=v2; sAT[c4+3][r]=v3;
    }
    #pragma unroll
    for(int it=0; it<4; ++it){
      int gli = t + it*256;
      int r = gli>>4, c4 = (gli&15)*4;
      int gk = kc*64 + r;
      float4 wv = (c4<32) ? *reinterpret_cast<const float4*>(&Wmix[(size_t)gk*32 + c4])
                          : *reinterpret_cast<const float4*>(&Wmix[6144 + (size_t)gk*32 + (c4-32)]);
      *reinterpret_cast<float4*>(&sW[r][c4]) = wv;
    }
    __syncthreads();
    #pragma unroll 8
    for(int k=0;k<64;++k){
      const float4 av = *reinterpret_cast<const float4*>(&sAT[k][tr*4]);
      const float4 wv = *reinterpret_cast<const float4*>(&sW[k][tc*4]);
      acc[0][0]+=av.x*wv.x; acc[0][1]+=av.x*wv.y; acc[0][2]+=av.x*wv.z; acc[0][3]+=av.x*wv.w;
      acc[1][0]+=av.y*wv.x; acc[1][1]+=av.y*wv.y; acc[1][2]+=av.y*wv.z; acc[1][3]+=av.y*wv.w;
      acc[2][0]+=av.z*wv.x; acc[2][1]+=av.z*wv.y; acc[2][2]+=av.z*wv.z; acc[2][3]+=av.z*wv.w;
      acc[3][0]+=av.w*wv.x; acc[3][1]+=av.w*wv.y; acc[3][2]+=av.w*wv.z; acc[3][3]+=av.w*wv.w;
    }
    __syncthreads();
  }
  #pragma unroll
  for(int i=0;i<4;++i){
    int m=m0+tr*4+i;
    if(m<M){
      #pragma unroll
      for(int j=0;j<4;++j){
        int c=tc*4+j;
        if(c<32) Z0[(size_t)m*32+c]=acc[i][j];
        else     Z1[(size_t)m*32+(c-32)]=f2b(acc[i][j]);
      }
    }
  }
}

// ---------------- sparse prop + Clenshaw combine ----------------
// acc = sum_e w_e * Bin[src_e][f]  (L_hat t = -acc); w_e packed with src.
// Predicated chunks of 8 -> 8 independent row-gathers in flight incl. tail.
// MODE 0: out = Z - 2*acc
// MODE 1: out = Z - 2*acc - Bsub
// MODE 2: out = relu(Z - acc - Bsub + bias) + Zs + bias2
// MODE 3: out = Z - acc + bias
template<int F, int MODE, typename OT>
__global__ __launch_bounds__(256) void k_prop(const int* __restrict__ row_ptr, const int2* __restrict__ csr_ew,
    const bf16* __restrict__ Bin,
    const float* __restrict__ Z, const bf16* __restrict__ Bsub,
    const float* __restrict__ bias, const bf16* __restrict__ Zs, const float* __restrict__ bias2,
    OT* __restrict__ out, int N){
  constexpr int NPB = 256/F;
  int v = blockIdx.x*NPB + threadIdx.x/F;
  if(v>=N) return;
  int f = threadIdx.x % F;
  int e0=row_ptr[v], e1=row_ptr[v+1];
  float acc=0.f;
  for(int e=e0; e<e1; e+=8){
    float vv[8], ww[8];
    #pragma unroll
    for(int j=0;j<8;++j){
      int idx = e+j;
      int2 p = csr_ew[idx<e1 ? idx : e0];
      ww[j] = (idx<e1) ? __int_as_float(p.y) : 0.f;
      vv[j] = b2f(Bin[(unsigned)p.x*F + f]);
    }
    #pragma unroll
    for(int j=0;j<8;++j) acc += ww[j]*vv[j];
  }
  unsigned idx=(unsigned)v*F+f;
  float r;
  if(MODE==0)      r = Z[idx] - 2.f*acc;
  else if(MODE==1) r = Z[idx] - 2.f*acc - b2f(Bsub[idx]);
  else if(MODE==2){ float tv = Z[idx] - acc - b2f(Bsub[idx]) + bias[f];
                    r = fmaxf(tv,0.f) + b2f(Zs[idx]) + bias2[f]; }
  else             r = Z[idx] - acc + bias[f];
  stf(&out[idx], r);
}

// ---------------- host ----------------

static void launch_gemm(int K, bool bout, const bf16* A, const float* W, float* Cf, bf16* Cb, int M, hipStream_t st){
  int grid=(M+63)/64;
  if(K==128){
    if(bout) k_gemm<128,true ><<<grid,256,0,st>>>(A,W,Cf,Cb,M);
    else     k_gemm<128,false><<<grid,256,0,st>>>(A,W,Cf,Cb,M);
  } else {
    if(bout) k_gemm<64,true ><<<grid,256,0,st>>>(A,W,Cf,Cb,M);
    else     k_gemm<64,false><<<grid,256,0,st>>>(A,W,Cf,Cb,M);
  }
}

extern "C" void kernel_launch(void* const* d_in, const int* in_sizes, int n_in,
                              void* d_out, int out_size, void* d_ws, size_t ws_size,
                              hipStream_t stream) {
  const int N = in_sizes[0]/128;     // 100000
  const int E = in_sizes[1]/2;       // 3200000

  const float* x    = (const float*)d_in[0];
  const int*   ei   = (const int*  )d_in[1];
  const float* W0   = (const float*)d_in[2];
  const float* b0   = (const float*)d_in[3];
  const float* Ws0  = (const float*)d_in[4];
  const float* bs0  = (const float*)d_in[5];
  const float* W1   = (const float*)d_in[6];
  const float* b1   = (const float*)d_in[7];
  const float* Ws1  = (const float*)d_in[8];
  const float* bs1  = (const float*)d_in[9];
  const float* W2   = (const float*)d_in[10];
  const float* b2   = (const float*)d_in[11];
  const float* Ws2  = (const float*)d_in[12];
  const float* bs2  = (const float*)d_in[13];
  const float* Wmix = (const float*)d_in[14];
  const float* bmix = (const float*)d_in[15];
  float* out = (float*)d_out;

  const int* src = ei;
  const int* dst = ei + E;

  // workspace carve (~150 MB)
  size_t off=0;
  char* ws=(char*)d_ws;
  auto alloc=[&](size_t bytes)->void*{ void* p = ws+off; off=(off+bytes+255)&~(size_t)255; return p; };
  int2*  csr_ew  = (int2*) alloc((size_t)E*8);
  int*   row_ptr = (int*)  alloc((size_t)(N+1)*4);
  int*   cursor  = (int*)  alloc((size_t)N*4);
  int*   deg     = (int*)  alloc((size_t)N*4);
  float* dis     = (float*)alloc((size_t)N*4);
  int*   bsums   = (int*)  alloc(2048);
  int*   boffs   = (int*)  alloc(2048);
  float* Zk      = (float*)alloc((size_t)N*64*4);
  bf16*  Zsb     = (bf16*) alloc((size_t)N*64*2);
  bf16*  Bb0     = (bf16*) alloc((size_t)N*64*2);
  bf16*  Bb1     = (bf16*) alloc((size_t)N*64*2);
  bf16*  Bb2     = (bf16*) alloc((size_t)N*64*2);
  bf16*  hA      = (bf16*) alloc((size_t)N*64*2);
  bf16*  hB      = (bf16*) alloc((size_t)N*64*2);
  bf16*  xb      = (bf16*) alloc((size_t)N*128*2);
  if(off > ws_size){
    fprintf(stderr, "kernel_launch: workspace too small: need %zu, have %zu\n", off, ws_size);
    return;
  }

  const int NB   = (N+255)/256;   // 391
  const int gE   = (E+255)/256;
  const int gP64 = (N+3)/4;
  const int gP32 = (N+7)/8;

  // graph prep + x cast
  hipMemsetAsync(deg, 0, (size_t)N*4, stream);
  hipMemsetAsync(cursor, 0, (size_t)N*4, stream);
  k_cast<<<(N*128/4+255)/256,256,0,stream>>>(x, xb, N*128/4);
  k_count<<<gE,256,0,stream>>>(dst, deg, E);
  k_scan1<<<NB,256,0,stream>>>(deg, row_ptr+1, bsums, N);
  k_scan2<<<1,512,0,stream>>>(bsums, boffs, NB);
  k_scan3<<<NB,256,0,stream>>>(row_ptr, boffs, deg, dis, N);
  k_fill<<<gE,256,0,stream>>>(src, dst, dis, row_ptr, cursor, csr_ew, E);

  // one ChebConv layer via Clenshaw:
  // B5=Z5; B4=Z4-2a(B5); B3=Z3-2a(B4)-B5; B2=Z2-2a(B3)-B4; B1=Z1-2a(B2)-B3;
  // h' = relu(Z0 - a(B1) - B2 + b) + (h@Ws + bs)
  auto LAYER=[&](const bf16* hin, int K, const float* W, const float* b, const float* Ws, const float* bs, bf16* hout){
    size_t WK=(size_t)K*64;
    launch_gemm(K,true ,hin,Ws,    nullptr,Zsb,N,stream);                   // skip branch
    launch_gemm(K,true ,hin,W+5*WK,nullptr,Bb0,N,stream);                   // B5
    launch_gemm(K,false,hin,W+4*WK,Zk,nullptr,N,stream);
    k_prop<64,0,bf16><<<gP64,256,0,stream>>>(row_ptr,csr_ew,Bb0,Zk,nullptr,nullptr,nullptr,nullptr,Bb1,N); // B4
    launch_gemm(K,false,hin,W+3*WK,Zk,nullptr,N,stream);
    k_prop<64,1,bf16><<<gP64,256,0,stream>>>(row_ptr,csr_ew,Bb1,Zk,Bb0,nullptr,nullptr,nullptr,Bb2,N);     // B3
    launch_gemm(K,false,hin,W+2*WK,Zk,nullptr,N,stream);
    k_prop<64,1,bf16><<<gP64,256,0,stream>>>(row_ptr,csr_ew,Bb2,Zk,Bb1,nullptr,nullptr,nullptr,Bb0,N);     // B2
    launch_gemm(K,false,hin,W+1*WK,Zk,nullptr,N,stream);
    k_prop<64,1,bf16><<<gP64,256,0,stream>>>(row_ptr,csr_ew,Bb0,Zk,Bb2,nullptr,nullptr,nullptr,Bb1,N);     // B1
    launch_gemm(K,false,hin,W+0*WK,Zk,nullptr,N,stream);
    k_prop<64,2,bf16><<<gP64,256,0,stream>>>(row_ptr,csr_ew,Bb1,Zk,Bb0,b,Zsb,bs,hout,N);                   // h'
  };

  LAYER(xb, 128, W0, b0, Ws0, bs0, hA);
  LAYER(hA,  64, W1, b1, Ws1, bs1, hB);
  LAYER(hB,  64, W2, b2, Ws2, bs2, hA);

  // mix head: out = Z0m + L_hat(Z1m) + bmix,  hcat = [hA | xb]
  k_gemm_mix<<<(N+63)/64,256,0,stream>>>(hA, xb, Wmix, Zk, Bb0, N);
  k_prop<32,3,float><<<gP32,256,0,stream>>>(row_ptr,csr_ew,Bb0,Zk,nullptr,bmix,nullptr,nullptr,out,N);
}

// Round 6
// 2425.098 us; speedup vs baseline: 1.6151x; 1.6151x over previous
//
#include <hip/hip_runtime.h>
#include <hip/hip_bf16.h>
#include <cstdio>
#include <cstdint>

typedef __hip_bfloat16 bf16;

struct __align__(8) bf16x4 { bf16 x,y,z,w; };

static __device__ __forceinline__ float b2f(bf16 v){ return __bfloat162float(v); }
static __device__ __forceinline__ bf16  f2b(float v){ return __float2bfloat16(v); }
static __device__ __forceinline__ void  stf(float* p, float v){ *p = v; }
static __device__ __forceinline__ void  stf(bf16*  p, float v){ *p = f2b(v); }

// ---------------- graph prep ----------------

__global__ void k_cast(const float* __restrict__ x, bf16* __restrict__ xb, int n4){
  int i = blockIdx.x*256 + threadIdx.x;
  if(i<n4){
    float4 v = reinterpret_cast<const float4*>(x)[i];
    bf16x4 o{f2b(v.x),f2b(v.y),f2b(v.z),f2b(v.w)};
    reinterpret_cast<bf16x4*>(xb)[i] = o;
  }
}

__global__ void k_count(const int* __restrict__ dst, int* __restrict__ deg, int E){
  int e = blockIdx.x*256 + threadIdx.x;
  if(e<E) atomicAdd(&deg[dst[e]], 1);
}

__global__ void k_scan1(const int* __restrict__ deg, int* __restrict__ rp1, int* __restrict__ bsums, int N){
  __shared__ int s[256];
  int i = blockIdx.x*256 + threadIdx.x;
  int v = (i<N)? deg[i] : 0;
  s[threadIdx.x]=v; __syncthreads();
  for(int off=1; off<256; off<<=1){
    int t = (threadIdx.x>=off)? s[threadIdx.x-off] : 0;
    __syncthreads();
    s[threadIdx.x]+=t;
    __syncthreads();
  }
  if(i<N) rp1[i]=s[threadIdx.x];
  if(threadIdx.x==255) bsums[blockIdx.x]=s[255];
}

__global__ void k_scan2(const int* __restrict__ bsums, int* __restrict__ boffs, int NB){
  __shared__ int s[512];
  int x=threadIdx.x;
  int v = (x<NB)? bsums[x] : 0;
  s[x]=v; __syncthreads();
  for(int off=1; off<512; off<<=1){
    int t=(x>=off)? s[x-off]:0; __syncthreads();
    s[x]+=t; __syncthreads();
  }
  if(x<NB) boffs[x]=s[x]-v;  // exclusive prefix
}

__global__ void k_scan3(int* __restrict__ row_ptr, const int* __restrict__ boffs,
                        const int* __restrict__ deg, float* __restrict__ dis, int N){
  int i = blockIdx.x*256+threadIdx.x;
  if(i<N){
    row_ptr[i+1] += boffs[blockIdx.x];
    int d = deg[i];
    dis[i] = (d>0)? rsqrtf((float)d) : 0.f;
    if(i==0) row_ptr[0]=0;
  }
}

// CSR fill: packed {src, w} per edge -> ONE 8B scatter (r4: this fixed k_fill).
__global__ void k_fill(const int* __restrict__ src, const int* __restrict__ dst, const float* __restrict__ dis,
                       const int* __restrict__ row_ptr, int* __restrict__ cursor,
                       int2* __restrict__ csr_ew, int E){
  int e = blockIdx.x*256+threadIdx.x;
  if(e<E){
    int d = dst[e], s = src[e];
    int pos = row_ptr[d] + atomicAdd(&cursor[d], 1);
    float w = dis[s]*dis[d];
    csr_ew[pos] = make_int2(s, __float_as_int(w));
  }
}

// ---------------- dense GEMM: C[Mx64] = A[MxK] @ W[Kx64] ----------------
// A bf16 (vec4 staged), W f32 (float4 staged); f32 accumulate; out f32 or bf16.
// sAT transposed [k][row] so inner loop reads are aligned ds_read_b128.

template<int K, bool BOUT>
__global__ __launch_bounds__(256,2) void k_gemm(const bf16* __restrict__ A, const float* __restrict__ W,
                                                float* __restrict__ Cf, bf16* __restrict__ Cb, int M){
  __shared__ float sAT[64][68];
  __shared__ float sW[64][64];
  const int t = threadIdx.x;
  const int m0 = blockIdx.x*64;
  const int tr = t>>4, tc = t&15;
  float acc[4][4] = {};
  for(int kc=0; kc<K/64; ++kc){
    #pragma unroll
    for(int it=0; it<4; ++it){
      int gli = t + it*256;       // vec4 index, 16 per row
      int r = gli>>4, c4 = (gli&15)*4;
      int m = m0 + r;
      float v0=0,v1=0,v2=0,v3=0;
      if(m < M){
        bf16x4 u = *reinterpret_cast<const bf16x4*>(&A[(size_t)m*K + kc*64 + c4]);
        v0=b2f(u.x); v1=b2f(u.y); v2=b2f(u.z); v3=b2f(u.w);
      }
      sAT[c4+0][r]=v0; sAT[c4+1][r]=v1; sAT[c4+2][r]=v2; sAT[c4+3][r]=v3;
    }
    #pragma unroll
    for(int it=0; it<4; ++it){
      int gli = t + it*256;
      int r = gli>>4, c4 = (gli&15)*4;
      float4 wv = *reinterpret_cast<const float4*>(&W[(size_t)(kc*64+r)*64 + c4]);
      *reinterpret_cast<float4*>(&sW[r][c4]) = wv;
    }
    __syncthreads();
    #pragma unroll 8
    for(int k=0;k<64;++k){
      const float4 av = *reinterpret_cast<const float4*>(&sAT[k][tr*4]);
      const float4 wv = *reinterpret_cast<const float4*>(&sW[k][tc*4]);
      acc[0][0]+=av.x*wv.x; acc[0][1]+=av.x*wv.y; acc[0][2]+=av.x*wv.z; acc[0][3]+=av.x*wv.w;
      acc[1][0]+=av.y*wv.x; acc[1][1]+=av.y*wv.y; acc[1][2]+=av.y*wv.z; acc[1][3]+=av.y*wv.w;
      acc[2][0]+=av.z*wv.x; acc[2][1]+=av.z*wv.y; acc[2][2]+=av.z*wv.z; acc[2][3]+=av.z*wv.w;
      acc[3][0]+=av.w*wv.x; acc[3][1]+=av.w*wv.y; acc[3][2]+=av.w*wv.z; acc[3][3]+=av.w*wv.w;
    }
    __syncthreads();
  }
  #pragma unroll
  for(int i=0;i<4;++i){
    int m = m0 + tr*4 + i;
    if(m<M){
      #pragma unroll
      for(int j=0;j<4;++j){
        int c = tc*4+j;
        if(BOUT) Cb[(size_t)m*64+c] = f2b(acc[i][j]);
        else     Cf[(size_t)m*64+c] = acc[i][j];
      }
    }
  }
}

// mix GEMM: A = [h(64) | xb(128)] bf16 (M x 192), W = [Wmix0 | Wmix1] (192 x (32+32))
// out: cols 0..31 -> Z0 (f32), cols 32..63 -> Z1 (bf16)
__global__ __launch_bounds__(256,2) void k_gemm_mix(const bf16* __restrict__ h, const bf16* __restrict__ xb,
     const float* __restrict__ Wmix, float* __restrict__ Z0, bf16* __restrict__ Z1, int M){
  __shared__ float sAT[64][68];
  __shared__ float sW[64][64];
  const int t=threadIdx.x, m0=blockIdx.x*64, tr=t>>4, tc=t&15;
  float acc[4][4]={};
  for(int kc=0;kc<3;++kc){
    #pragma unroll
    for(int it=0; it<4; ++it){
      int gli = t + it*256;
      int r = gli>>4, c4 = (gli&15)*4;
      int m = m0 + r;
      float v0=0,v1=0,v2=0,v3=0;
      if(m < M){
        bf16x4 u = (kc==0) ? *reinterpret_cast<const bf16x4*>(&h[(size_t)m*64 + c4])
                           : *reinterpret_cast<const bf16x4*>(&xb[(size_t)m*128 + (kc-1)*64 + c4]);
        v0=b2f(u.x); v1=b2f(u.y); v2=b2f(u.z); v3=b2f(u.w);
      }
      sAT[c4+0][r]=v0; sAT[c4+1][r]=v1; sAT[c4+2][r]=v2; sAT[c4+3][r]=v3;
    }
    #pragma unroll
    for(int it=0; it<4; ++it){
      int gli = t + it*256;
      int r = gli>>4, c4 = (gli&15)*4;
      int gk = kc*64 + r;
      float4 wv = (c4<32) ? *reinterpret_cast<const float4*>(&Wmix[(size_t)gk*32 + c4])
                          : *reinterpret_cast<const float4*>(&Wmix[6144 + (size_t)gk*32 + (c4-32)]);
      *reinterpret_cast<float4*>(&sW[r][c4]) = wv;
    }
    __syncthreads();
    #pragma unroll 8
    for(int k=0;k<64;++k){
      const float4 av = *reinterpret_cast<const float4*>(&sAT[k][tr*4]);
      const float4 wv = *reinterpret_cast<const float4*>(&sW[k][tc*4]);
      acc[0][0]+=av.x*wv.x; acc[0][1]+=av.x*wv.y; acc[0][2]+=av.x*wv.z; acc[0][3]+=av.x*wv.w;
      acc[1][0]+=av.y*wv.x; acc[1][1]+=av.y*wv.y; acc[1][2]+=av.y*wv.z; acc[1][3]+=av.y*wv.w;
      acc[2][0]+=av.z*wv.x; acc[2][1]+=av.z*wv.y; acc[2][2]+=av.z*wv.z; acc[2][3]+=av.z*wv.w;
      acc[3][0]+=av.w*wv.x; acc[3][1]+=av.w*wv.y; acc[3][2]+=av.w*wv.z; acc[3][3]+=av.w*wv.w;
    }
    __syncthreads();
  }
  #pragma unroll
  for(int i=0;i<4;++i){
    int m=m0+tr*4+i;
    if(m<M){
      #pragma unroll
      for(int j=0;j<4;++j){
        int c=tc*4+j;
        if(c<32) Z0[(size_t)m*32+c]=acc[i][j];
        else     Z1[(size_t)m*32+(c-32)]=f2b(acc[i][j]);
      }
    }
  }
}

// ---------------- sparse prop + Clenshaw combine ----------------
// acc = sum_e w_e * Bin[src_e][f]  (L_hat t = -acc); w_e packed with src.
// Round-3 loop shape: UNPREDICATED full 8-chunks (consecutive constant-offset
// loads the compiler can merge) + serial tail. Rounds 4/5 showed a clamped
// index (`idx<e1?idx:e0`) defeats load merging and doubles kernel time.
// MODE 0: out = Z - 2*acc
// MODE 1: out = Z - 2*acc - Bsub
// MODE 2: out = relu(Z - acc - Bsub + bias) + Zs + bias2
// MODE 3: out = Z - acc + bias
template<int F, int MODE, typename OT>
__global__ __launch_bounds__(256) void k_prop(const int* __restrict__ row_ptr, const int2* __restrict__ csr_ew,
    const bf16* __restrict__ Bin,
    const float* __restrict__ Z, const bf16* __restrict__ Bsub,
    const float* __restrict__ bias, const bf16* __restrict__ Zs, const float* __restrict__ bias2,
    OT* __restrict__ out, int N){
  constexpr int NPB = 256/F;
  int v = blockIdx.x*NPB + threadIdx.x/F;
  if(v>=N) return;
  int f = threadIdx.x % F;
  int e0=row_ptr[v], e1=row_ptr[v+1];
  float acc=0.f;
  int e=e0;
  for(; e+8<=e1; e+=8){
    int2 p[8];
    #pragma unroll
    for(int j=0;j<8;++j) p[j] = csr_ew[e+j];
    float vv[8];
    #pragma unroll
    for(int j=0;j<8;++j) vv[j] = b2f(Bin[(unsigned)p[j].x*F + f]);
    #pragma unroll
    for(int j=0;j<8;++j) acc += __int_as_float(p[j].y)*vv[j];
  }
  for(; e<e1; ++e){
    int2 p = csr_ew[e];
    acc += __int_as_float(p.y) * b2f(Bin[(unsigned)p.x*F + f]);
  }
  unsigned idx=(unsigned)v*F+f;
  float r;
  if(MODE==0)      r = Z[idx] - 2.f*acc;
  else if(MODE==1) r = Z[idx] - 2.f*acc - b2f(Bsub[idx]);
  else if(MODE==2){ float tv = Z[idx] - acc - b2f(Bsub[idx]) + bias[f];
                    r = fmaxf(tv,0.f) + b2f(Zs[idx]) + bias2[f]; }
  else             r = Z[idx] - acc + bias[f];
  stf(&out[idx], r);
}

// ---------------- host ----------------

static void launch_gemm(int K, bool bout, const bf16* A, const float* W, float* Cf, bf16* Cb, int M, hipStream_t st){
  int grid=(M+63)/64;
  if(K==128){
    if(bout) k_gemm<128,true ><<<grid,256,0,st>>>(A,W,Cf,Cb,M);
    else     k_gemm<128,false><<<grid,256,0,st>>>(A,W,Cf,Cb,M);
  } else {
    if(bout) k_gemm<64,true ><<<grid,256,0,st>>>(A,W,Cf,Cb,M);
    else     k_gemm<64,false><<<grid,256,0,st>>>(A,W,Cf,Cb,M);
  }
}

extern "C" void kernel_launch(void* const* d_in, const int* in_sizes, int n_in,
                              void* d_out, int out_size, void* d_ws, size_t ws_size,
                              hipStream_t stream) {
  const int N = in_sizes[0]/128;     // 100000
  const int E = in_sizes[1]/2;       // 3200000

  const float* x    = (const float*)d_in[0];
  const int*   ei   = (const int*  )d_in[1];
  const float* W0   = (const float*)d_in[2];
  const float* b0   = (const float*)d_in[3];
  const float* Ws0  = (const float*)d_in[4];
  const float* bs0  = (const float*)d_in[5];
  const float* W1   = (const float*)d_in[6];
  const float* b1   = (const float*)d_in[7];
  const float* Ws1  = (const float*)d_in[8];
  const float* bs1  = (const float*)d_in[9];
  const float* W2   = (const float*)d_in[10];
  const float* b2   = (const float*)d_in[11];
  const float* Ws2  = (const float*)d_in[12];
  const float* bs2  = (const float*)d_in[13];
  const float* Wmix = (const float*)d_in[14];
  const float* bmix = (const float*)d_in[15];
  float* out = (float*)d_out;

  const int* src = ei;
  const int* dst = ei + E;

  // workspace carve (~150 MB)
  size_t off=0;
  char* ws=(char*)d_ws;
  auto alloc=[&](size_t bytes)->void*{ void* p = ws+off; off=(off+bytes+255)&~(size_t)255; return p; };
  int2*  csr_ew  = (int2*) alloc((size_t)E*8);
  int*   row_ptr = (int*)  alloc((size_t)(N+1)*4);
  int*   cursor  = (int*)  alloc((size_t)N*4);
  int*   deg     = (int*)  alloc((size_t)N*4);
  float* dis     = (float*)alloc((size_t)N*4);
  int*   bsums   = (int*)  alloc(2048);
  int*   boffs   = (int*)  alloc(2048);
  float* Zk      = (float*)alloc((size_t)N*64*4);
  bf16*  Zsb     = (bf16*) alloc((size_t)N*64*2);
  bf16*  Bb0     = (bf16*) alloc((size_t)N*64*2);
  bf16*  Bb1     = (bf16*) alloc((size_t)N*64*2);
  bf16*  Bb2     = (bf16*) alloc((size_t)N*64*2);
  bf16*  hA      = (bf16*) alloc((size_t)N*64*2);
  bf16*  hB      = (bf16*) alloc((size_t)N*64*2);
  bf16*  xb      = (bf16*) alloc((size_t)N*128*2);
  if(off > ws_size){
    fprintf(stderr, "kernel_launch: workspace too small: need %zu, have %zu\n", off, ws_size);
    return;
  }

  const int NB   = (N+255)/256;   // 391
  const int gE   = (E+255)/256;
  const int gP64 = (N+3)/4;
  const int gP32 = (N+7)/8;

  // graph prep + x cast
  hipMemsetAsync(deg, 0, (size_t)N*4, stream);
  hipMemsetAsync(cursor, 0, (size_t)N*4, stream);
  k_cast<<<(N*128/4+255)/256,256,0,stream>>>(x, xb, N*128/4);
  k_count<<<gE,256,0,stream>>>(dst, deg, E);
  k_scan1<<<NB,256,0,stream>>>(deg, row_ptr+1, bsums, N);
  k_scan2<<<1,512,0,stream>>>(bsums, boffs, NB);
  k_scan3<<<NB,256,0,stream>>>(row_ptr, boffs, deg, dis, N);
  k_fill<<<gE,256,0,stream>>>(src, dst, dis, row_ptr, cursor, csr_ew, E);

  // one ChebConv layer via Clenshaw:
  // B5=Z5; B4=Z4-2a(B5); B3=Z3-2a(B4)-B5; B2=Z2-2a(B3)-B4; B1=Z1-2a(B2)-B3;
  // h' = relu(Z0 - a(B1) - B2 + b) + (h@Ws + bs)
  auto LAYER=[&](const bf16* hin, int K, const float* W, const float* b, const float* Ws, const float* bs, bf16* hout){
    size_t WK=(size_t)K*64;
    launch_gemm(K,true ,hin,Ws,    nullptr,Zsb,N,stream);                   // skip branch
    launch_gemm(K,true ,hin,W+5*WK,nullptr,Bb0,N,stream);                   // B5
    launch_gemm(K,false,hin,W+4*WK,Zk,nullptr,N,stream);
    k_prop<64,0,bf16><<<gP64,256,0,stream>>>(row_ptr,csr_ew,Bb0,Zk,nullptr,nullptr,nullptr,nullptr,Bb1,N); // B4
    launch_gemm(K,false,hin,W+3*WK,Zk,nullptr,N,stream);
    k_prop<64,1,bf16><<<gP64,256,0,stream>>>(row_ptr,csr_ew,Bb1,Zk,Bb0,nullptr,nullptr,nullptr,Bb2,N);     // B3
    launch_gemm(K,false,hin,W+2*WK,Zk,nullptr,N,stream);
    k_prop<64,1,bf16><<<gP64,256,0,stream>>>(row_ptr,csr_ew,Bb2,Zk,Bb1,nullptr,nullptr,nullptr,Bb0,N);     // B2
    launch_gemm(K,false,hin,W+1*WK,Zk,nullptr,N,stream);
    k_prop<64,1,bf16><<<gP64,256,0,stream>>>(row_ptr,csr_ew,Bb0,Zk,Bb2,nullptr,nullptr,nullptr,Bb1,N);     // B1
    launch_gemm(K,false,hin,W+0*WK,Zk,nullptr,N,stream);
    k_prop<64,2,bf16><<<gP64,256,0,stream>>>(row_ptr,csr_ew,Bb1,Zk,Bb0,b,Zsb,bs,hout,N);                   // h'
  };

  LAYER(xb, 128, W0, b0, Ws0, bs0, hA);
  LAYER(hA,  64, W1, b1, Ws1, bs1, hB);
  LAYER(hB,  64, W2, b2, Ws2, bs2, hA);

  // mix head: out = Z0m + L_hat(Z1m) + bmix,  hcat = [hA | xb]
  k_gemm_mix<<<(N+63)/64,256,0,stream>>>(hA, xb, Wmix, Zk, Bb0, N);
  k_prop<32,3,float><<<gP32,256,0,stream>>>(row_ptr,csr_ew,Bb0,Zk,nullptr,bmix,nullptr,nullptr,out,N);
}

// Round 7
// 1897.906 us; speedup vs baseline: 2.0637x; 1.2778x over previous
//
#include <hip/hip_runtime.h>
#include <hip/hip_bf16.h>
#include <cstdio>
#include <cstdint>

typedef __hip_bfloat16 bf16;

struct __align__(8) bf16x4 { bf16 x,y,z,w; };

static __device__ __forceinline__ float b2f(bf16 v){ return __bfloat162float(v); }
static __device__ __forceinline__ bf16  f2b(float v){ return __float2bfloat16(v); }
static __device__ __forceinline__ float ldf(const float* p){ return *p; }
static __device__ __forceinline__ float ldf(const bf16* p){ return b2f(*p); }
static __device__ __forceinline__ void  stf(float* p, float v){ *p = v; }
static __device__ __forceinline__ void  stf(bf16*  p, float v){ *p = f2b(v); }

// ---------------- graph prep ----------------

__global__ void k_count(const int* __restrict__ dst, int* __restrict__ deg, int E){
  int e = blockIdx.x*256 + threadIdx.x;
  if(e<E) atomicAdd(&deg[dst[e]], 1);
}

__global__ void k_scan1(const int* __restrict__ deg, int* __restrict__ rp1, int* __restrict__ bsums, int N){
  __shared__ int s[256];
  int i = blockIdx.x*256 + threadIdx.x;
  int v = (i<N)? deg[i] : 0;
  s[threadIdx.x]=v; __syncthreads();
  for(int off=1; off<256; off<<=1){
    int t = (threadIdx.x>=off)? s[threadIdx.x-off] : 0;
    __syncthreads();
    s[threadIdx.x]+=t;
    __syncthreads();
  }
  if(i<N) rp1[i]=s[threadIdx.x];
  if(threadIdx.x==255) bsums[blockIdx.x]=s[255];
}

__global__ void k_scan2(const int* __restrict__ bsums, int* __restrict__ boffs, int NB){
  __shared__ int s[512];
  int x=threadIdx.x;
  int v = (x<NB)? bsums[x] : 0;
  s[x]=v; __syncthreads();
  for(int off=1; off<512; off<<=1){
    int t=(x>=off)? s[x-off]:0; __syncthreads();
    s[x]+=t; __syncthreads();
  }
  if(x<NB) boffs[x]=s[x]-v;  // exclusive prefix
}

__global__ void k_scan3(int* __restrict__ row_ptr, const int* __restrict__ boffs,
                        const int* __restrict__ deg, float* __restrict__ dis, int N){
  int i = blockIdx.x*256+threadIdx.x;
  if(i<N){
    row_ptr[i+1] += boffs[blockIdx.x];
    int d = deg[i];
    dis[i] = (d>0)? rsqrtf((float)d) : 0.f;
    if(i==0) row_ptr[0]=0;
  }
}

// CSR fill: src index ONLY (4B scatter; weights factorized into pre-scaled
// feature buffers -> k_fill scatter traffic halves vs int2).
__global__ void k_fill(const int* __restrict__ src, const int* __restrict__ dst,
                       const int* __restrict__ row_ptr, int* __restrict__ cursor,
                       int* __restrict__ csr_src, int E){
  int e = blockIdx.x*256+threadIdx.x;
  if(e<E){
    int d = dst[e];
    int pos = row_ptr[d] + atomicAdd(&cursor[d], 1);
    csr_src[pos]=src[e];
  }
}

// ---------------- dense GEMM: C[Mx64] = A[MxK] @ W[Kx64] ----------------
// OUTK: 0 -> f32 Cf; 1 -> bf16 Cb; 2 -> bf16 Cb + pre-scaled bf16 Cs (dis[m]*val)

template<int K, typename AT, int OUTK>
__global__ __launch_bounds__(256,2) void k_gemm(const AT* __restrict__ A, const float* __restrict__ W,
                                                float* __restrict__ Cf, bf16* __restrict__ Cb,
                                                bf16* __restrict__ Cs, const float* __restrict__ dis, int M){
  __shared__ float sAT[64][68];
  __shared__ float sW[64][64];
  const int t = threadIdx.x;
  const int m0 = blockIdx.x*64;
  const int tr = t>>4, tc = t&15;
  float acc[4][4] = {};
  for(int kc=0; kc<K/64; ++kc){
    #pragma unroll
    for(int it=0; it<4; ++it){
      int gli = t + it*256;       // vec4 index, 16 per row
      int r = gli>>4, c4 = (gli&15)*4;
      int m = m0 + r;
      float v0=0,v1=0,v2=0,v3=0;
      if(m < M){
        const AT* ap = &A[(size_t)m*K + kc*64 + c4];
        v0=ldf(ap+0); v1=ldf(ap+1); v2=ldf(ap+2); v3=ldf(ap+3);
      }
      sAT[c4+0][r]=v0; sAT[c4+1][r]=v1; sAT[c4+2][r]=v2; sAT[c4+3][r]=v3;
    }
    #pragma unroll
    for(int it=0; it<4; ++it){
      int gli = t + it*256;
      int r = gli>>4, c4 = (gli&15)*4;
      float4 wv = *reinterpret_cast<const float4*>(&W[(size_t)(kc*64+r)*64 + c4]);
      *reinterpret_cast<float4*>(&sW[r][c4]) = wv;
    }
    __syncthreads();
    #pragma unroll 8
    for(int k=0;k<64;++k){
      const float4 av = *reinterpret_cast<const float4*>(&sAT[k][tr*4]);
      const float4 wv = *reinterpret_cast<const float4*>(&sW[k][tc*4]);
      acc[0][0]+=av.x*wv.x; acc[0][1]+=av.x*wv.y; acc[0][2]+=av.x*wv.z; acc[0][3]+=av.x*wv.w;
      acc[1][0]+=av.y*wv.x; acc[1][1]+=av.y*wv.y; acc[1][2]+=av.y*wv.z; acc[1][3]+=av.y*wv.w;
      acc[2][0]+=av.z*wv.x; acc[2][1]+=av.z*wv.y; acc[2][2]+=av.z*wv.z; acc[2][3]+=av.z*wv.w;
      acc[3][0]+=av.w*wv.x; acc[3][1]+=av.w*wv.y; acc[3][2]+=av.w*wv.z; acc[3][3]+=av.w*wv.w;
    }
    __syncthreads();
  }
  #pragma unroll
  for(int i=0;i<4;++i){
    int m = m0 + tr*4 + i;
    if(m<M){
      float dm = (OUTK==2) ? dis[m] : 0.f;
      #pragma unroll
      for(int j=0;j<4;++j){
        int c = tc*4+j;
        if(OUTK==0) Cf[(size_t)m*64+c] = acc[i][j];
        else        Cb[(size_t)m*64+c] = f2b(acc[i][j]);
        if(OUTK==2) Cs[(size_t)m*64+c] = f2b(acc[i][j]*dm);
      }
    }
  }
}

// mix GEMM: A = [h(64,bf16) | x(128,f32)] (M x 192), W = [Wmix0|Wmix1] (192 x (32+32))
// cols 0..31 -> Z0 (f32); cols 32..63 -> Z1s (bf16, PRE-SCALED by dis[m])
__global__ __launch_bounds__(256,2) void k_gemm_mix(const bf16* __restrict__ h, const float* __restrict__ x,
     const float* __restrict__ Wmix, float* __restrict__ Z0, bf16* __restrict__ Z1s,
     const float* __restrict__ dis, int M){
  __shared__ float sAT[64][68];
  __shared__ float sW[64][64];
  const int t=threadIdx.x, m0=blockIdx.x*64, tr=t>>4, tc=t&15;
  float acc[4][4]={};
  for(int kc=0;kc<3;++kc){
    #pragma unroll
    for(int it=0; it<4; ++it){
      int gli = t + it*256;
      int r = gli>>4, c4 = (gli&15)*4;
      int m = m0 + r;
      float v0=0,v1=0,v2=0,v3=0;
      if(m < M){
        if(kc==0){
          bf16x4 u = *reinterpret_cast<const bf16x4*>(&h[(size_t)m*64 + c4]);
          v0=b2f(u.x); v1=b2f(u.y); v2=b2f(u.z); v3=b2f(u.w);
        } else {
          float4 u = *reinterpret_cast<const float4*>(&x[(size_t)m*128 + (kc-1)*64 + c4]);
          v0=u.x; v1=u.y; v2=u.z; v3=u.w;
        }
      }
      sAT[c4+0][r]=v0; sAT[c4+1][r]=v1; sAT[c4+2][r]=v2; sAT[c4+3][r]=v3;
    }
    #pragma unroll
    for(int it=0; it<4; ++it){
      int gli = t + it*256;
      int r = gli>>4, c4 = (gli&15)*4;
      int gk = kc*64 + r;
      float4 wv = (c4<32) ? *reinterpret_cast<const float4*>(&Wmix[(size_t)gk*32 + c4])
                          : *reinterpret_cast<const float4*>(&Wmix[6144 + (size_t)gk*32 + (c4-32)]);
      *reinterpret_cast<float4*>(&sW[r][c4]) = wv;
    }
    __syncthreads();
    #pragma unroll 8
    for(int k=0;k<64;++k){
      const float4 av = *reinterpret_cast<const float4*>(&sAT[k][tr*4]);
      const float4 wv = *reinterpret_cast<const float4*>(&sW[k][tc*4]);
      acc[0][0]+=av.x*wv.x; acc[0][1]+=av.x*wv.y; acc[0][2]+=av.x*wv.z; acc[0][3]+=av.x*wv.w;
      acc[1][0]+=av.y*wv.x; acc[1][1]+=av.y*wv.y; acc[1][2]+=av.y*wv.z; acc[1][3]+=av.y*wv.w;
      acc[2][0]+=av.z*wv.x; acc[2][1]+=av.z*wv.y; acc[2][2]+=av.z*wv.z; acc[2][3]+=av.z*wv.w;
      acc[3][0]+=av.w*wv.x; acc[3][1]+=av.w*wv.y; acc[3][2]+=av.w*wv.z; acc[3][3]+=av.w*wv.w;
    }
    __syncthreads();
  }
  #pragma unroll
  for(int i=0;i<4;++i){
    int m=m0+tr*4+i;
    if(m<M){
      float dm = dis[m];
      #pragma unroll
      for(int j=0;j<4;++j){
        int c=tc*4+j;
        if(c<32) Z0[(size_t)m*32+c]=acc[i][j];
        else     Z1s[(size_t)m*32+(c-32)]=f2b(acc[i][j]*dm);
      }
    }
  }
}

// ---------------- sparse prop + Clenshaw combine ----------------
// a = dis[v] * sum_e BinS[src_e][f]   (BinS pre-scaled by dis[src]); L_hat t = -a
// Weightless inner loop: 4B src idx (merges to dwordx4) + 128B row gather + add.
// Unroll 16 main, one unpredicated 8-chunk, then ONE predicated 8-chunk tail
// (clamp confined to <=1 chunk; r4/r5: whole-loop predication defeats merging).
// MODE 0: r = Z - 2a           -> outN(bf16) + outS
// MODE 1: r = Z - 2a - Bsub    -> outN + outS
// MODE 2: r = relu(Z - a - Bsub + bias) + Zs + bias2 -> outN only
// MODE 3: r = Z - a + bias     -> f32 out only
template<int F, int MODE, bool SOUT, typename OT>
__global__ __launch_bounds__(256) void k_prop(const int* __restrict__ row_ptr, const int* __restrict__ csr_src,
    const float* __restrict__ dis, const bf16* __restrict__ BinS,
    const float* __restrict__ Z, const bf16* __restrict__ Bsub,
    const float* __restrict__ bias, const bf16* __restrict__ Zs, const float* __restrict__ bias2,
    OT* __restrict__ outN, bf16* __restrict__ outS, int N){
  constexpr int NPB = 256/F;
  int v = blockIdx.x*NPB + threadIdx.x/F;
  if(v>=N) return;
  int f = threadIdx.x % F;
  int e0=row_ptr[v], e1=row_ptr[v+1];
  float acc=0.f;
  int e=e0;
  for(; e+16<=e1; e+=16){
    int s[16];
    #pragma unroll
    for(int j=0;j<16;++j) s[j]=csr_src[e+j];
    float vv[16];
    #pragma unroll
    for(int j=0;j<16;++j) vv[j]=b2f(BinS[(unsigned)s[j]*F + f]);
    #pragma unroll
    for(int j=0;j<16;++j) acc+=vv[j];
  }
  if(e+8<=e1){
    int s[8];
    #pragma unroll
    for(int j=0;j<8;++j) s[j]=csr_src[e+j];
    float vv[8];
    #pragma unroll
    for(int j=0;j<8;++j) vv[j]=b2f(BinS[(unsigned)s[j]*F + f]);
    #pragma unroll
    for(int j=0;j<8;++j) acc+=vv[j];
    e+=8;
  }
  if(e<e1){
    #pragma unroll
    for(int j=0;j<8;++j){
      int idx=e+j;
      int s=csr_src[idx<e1 ? idx : e0];
      float vv=b2f(BinS[(unsigned)s*F + f]);
      acc += (idx<e1)? vv : 0.f;
    }
  }
  float dv = dis[v];
  float a = dv*acc;
  unsigned idx=(unsigned)v*F+f;
  float r;
  if(MODE==0)      r = Z[idx] - 2.f*a;
  else if(MODE==1) r = Z[idx] - 2.f*a - b2f(Bsub[idx]);
  else if(MODE==2){ float tv = Z[idx] - a - b2f(Bsub[idx]) + bias[f];
                    r = fmaxf(tv,0.f) + b2f(Zs[idx]) + bias2[f]; }
  else             r = Z[idx] - a + bias[f];
  stf(&outN[idx], r);
  if(SOUT) outS[idx] = f2b(dv*r);
}

// ---------------- host ----------------

template<typename AT>
static void launch_gemm(int K, int outk, const AT* A, const float* W, float* Cf, bf16* Cb,
                        bf16* Cs, const float* dis, int M, hipStream_t st){
  int grid=(M+63)/64;
  if(K==128){
    if(outk==0)      k_gemm<128,AT,0><<<grid,256,0,st>>>(A,W,Cf,Cb,Cs,dis,M);
    else if(outk==1) k_gemm<128,AT,1><<<grid,256,0,st>>>(A,W,Cf,Cb,Cs,dis,M);
    else             k_gemm<128,AT,2><<<grid,256,0,st>>>(A,W,Cf,Cb,Cs,dis,M);
  } else {
    if(outk==0)      k_gemm<64,AT,0><<<grid,256,0,st>>>(A,W,Cf,Cb,Cs,dis,M);
    else if(outk==1) k_gemm<64,AT,1><<<grid,256,0,st>>>(A,W,Cf,Cb,Cs,dis,M);
    else             k_gemm<64,AT,2><<<grid,256,0,st>>>(A,W,Cf,Cb,Cs,dis,M);
  }
}

extern "C" void kernel_launch(void* const* d_in, const int* in_sizes, int n_in,
                              void* d_out, int out_size, void* d_ws, size_t ws_size,
                              hipStream_t stream) {
  const int N = in_sizes[0]/128;     // 100000
  const int E = in_sizes[1]/2;       // 3200000

  const float* x    = (const float*)d_in[0];
  const int*   ei   = (const int*  )d_in[1];
  const float* W0   = (const float*)d_in[2];
  const float* b0   = (const float*)d_in[3];
  const float* Ws0  = (const float*)d_in[4];
  const float* bs0  = (const float*)d_in[5];
  const float* W1   = (const float*)d_in[6];
  const float* b1   = (const float*)d_in[7];
  const float* Ws1  = (const float*)d_in[8];
  const float* bs1  = (const float*)d_in[9];
  const float* W2   = (const float*)d_in[10];
  const float* b2   = (const float*)d_in[11];
  const float* Ws2  = (const float*)d_in[12];
  const float* bs2  = (const float*)d_in[13];
  const float* Wmix = (const float*)d_in[14];
  const float* bmix = (const float*)d_in[15];
  float* out = (float*)d_out;

  const int* src = ei;
  const int* dst = ei + E;

  // workspace carve (~156 MB; <= proven footprint range)
  size_t off=0;
  char* ws=(char*)d_ws;
  auto alloc=[&](size_t bytes)->void*{ void* p = ws+off; off=(off+bytes+255)&~(size_t)255; return p; };
  int*   csr_src = (int*)  alloc((size_t)E*4);
  int*   row_ptr = (int*)  alloc((size_t)(N+1)*4);
  int*   cursor  = (int*)  alloc((size_t)N*4);
  int*   deg     = (int*)  alloc((size_t)N*4);
  float* dis     = (float*)alloc((size_t)N*4);
  int*   bsums   = (int*)  alloc(2048);
  int*   boffs   = (int*)  alloc(2048);
  float* Zk      = (float*)alloc((size_t)N*64*4);
  bf16*  Zsb     = (bf16*) alloc((size_t)N*64*2);
  bf16*  P0n     = (bf16*) alloc((size_t)N*64*2);
  bf16*  P0s     = (bf16*) alloc((size_t)N*64*2);
  bf16*  P1n     = (bf16*) alloc((size_t)N*64*2);
  bf16*  P1s     = (bf16*) alloc((size_t)N*64*2);
  bf16*  P2n     = (bf16*) alloc((size_t)N*64*2);
  bf16*  P2s     = (bf16*) alloc((size_t)N*64*2);
  bf16*  hA      = (bf16*) alloc((size_t)N*64*2);
  bf16*  hB      = (bf16*) alloc((size_t)N*64*2);
  if(off > ws_size){
    fprintf(stderr, "kernel_launch: workspace too small: need %zu, have %zu\n", off, ws_size);
    return;
  }

  const int NB   = (N+255)/256;   // 391
  const int gE   = (E+255)/256;
  const int gP64 = (N+3)/4;
  const int gP32 = (N+7)/8;

  // graph prep
  hipMemsetAsync(deg, 0, (size_t)N*4, stream);
  hipMemsetAsync(cursor, 0, (size_t)N*4, stream);
  k_count<<<gE,256,0,stream>>>(dst, deg, E);
  k_scan1<<<NB,256,0,stream>>>(deg, row_ptr+1, bsums, N);
  k_scan2<<<1,512,0,stream>>>(bsums, boffs, NB);
  k_scan3<<<NB,256,0,stream>>>(row_ptr, boffs, deg, dis, N);
  k_fill<<<gE,256,0,stream>>>(src, dst, row_ptr, cursor, csr_src, E);

  // one ChebConv layer via Clenshaw (B5..B1), pre-scaled gather buffers:
  // B5=Z5; B4=Z4-2a(B5); B3=Z3-2a(B4)-B5; B2=Z2-2a(B3)-B4; B1=Z1-2a(B2)-B3;
  // h' = relu(Z0 - a(B1) - B2 + b) + (h@Ws + bs)
  auto LAYER=[&](auto hin, int K, const float* W, const float* b, const float* Ws, const float* bs, bf16* hout){
    size_t WK=(size_t)K*64;
    launch_gemm(K,1,hin,Ws,    nullptr,Zsb,nullptr,dis,N,stream);           // skip branch
    launch_gemm(K,2,hin,W+5*WK,nullptr,P0n,P0s,dis,N,stream);               // B5 (n+s)
    launch_gemm(K,0,hin,W+4*WK,Zk,nullptr,nullptr,dis,N,stream);
    k_prop<64,0,true ,bf16><<<gP64,256,0,stream>>>(row_ptr,csr_src,dis,P0s,Zk,nullptr,nullptr,nullptr,nullptr,P1n,P1s,N); // B4
    launch_gemm(K,0,hin,W+3*WK,Zk,nullptr,nullptr,dis,N,stream);
    k_prop<64,1,true ,bf16><<<gP64,256,0,stream>>>(row_ptr,csr_src,dis,P1s,Zk,P0n,nullptr,nullptr,nullptr,P2n,P2s,N);     // B3
    launch_gemm(K,0,hin,W+2*WK,Zk,nullptr,nullptr,dis,N,stream);
    k_prop<64,1,true ,bf16><<<gP64,256,0,stream>>>(row_ptr,csr_src,dis,P2s,Zk,P1n,nullptr,nullptr,nullptr,P0n,P0s,N);     // B2
    launch_gemm(K,0,hin,W+1*WK,Zk,nullptr,nullptr,dis,N,stream);
    k_prop<64,1,true ,bf16><<<gP64,256,0,stream>>>(row_ptr,csr_src,dis,P0s,Zk,P2n,nullptr,nullptr,nullptr,P1n,P1s,N);     // B1
    launch_gemm(K,0,hin,W+0*WK,Zk,nullptr,nullptr,dis,N,stream);
    k_prop<64,2,false,bf16><<<gP64,256,0,stream>>>(row_ptr,csr_src,dis,P1s,Zk,P0n,b,Zsb,bs,hout,nullptr,N);               // h'
  };

  LAYER(x , 128, W0, b0, Ws0, bs0, hA);
  LAYER(hA,  64, W1, b1, Ws1, bs1, hB);
  LAYER(hB,  64, W2, b2, Ws2, bs2, hA);

  // mix head: out = Z0m + L_hat(Z1m) + bmix,  hcat = [hA | x]
  k_gemm_mix<<<(N+63)/64,256,0,stream>>>(hA, x, Wmix, Zk, P0s, dis, N);
  k_prop<32,3,false,float><<<gP32,256,0,stream>>>(row_ptr,csr_src,dis,P0s,Zk,nullptr,bmix,nullptr,nullptr,out,nullptr,N);
}

// Round 8
// 1811.582 us; speedup vs baseline: 2.1621x; 1.0477x over previous
//
#include <hip/hip_runtime.h>
#include <hip/hip_bf16.h>
#include <cstdio>
#include <cstdint>

typedef __hip_bfloat16 bf16;

static __device__ __forceinline__ float b2f(bf16 v){ return __bfloat162float(v); }
static __device__ __forceinline__ bf16  f2b(float v){ return __float2bfloat16(v); }
static __device__ __forceinline__ float ldf(const float* p){ return *p; }
static __device__ __forceinline__ float ldf(const bf16* p){ return b2f(*p); }
static __device__ __forceinline__ void  stf(float* p, float v){ *p = v; }
static __device__ __forceinline__ void  stf(bf16*  p, float v){ *p = f2b(v); }

// ---------------- graph prep ----------------

__global__ void k_count(const int* __restrict__ dst, int* __restrict__ deg, int E){
  int e = blockIdx.x*256 + threadIdx.x;
  if(e<E) atomicAdd(&deg[dst[e]], 1);
}

__global__ void k_scan1(const int* __restrict__ deg, int* __restrict__ rp1, int* __restrict__ bsums, int N){
  __shared__ int s[256];
  int i = blockIdx.x*256 + threadIdx.x;
  int v = (i<N)? deg[i] : 0;
  s[threadIdx.x]=v; __syncthreads();
  for(int off=1; off<256; off<<=1){
    int t = (threadIdx.x>=off)? s[threadIdx.x-off] : 0;
    __syncthreads();
    s[threadIdx.x]+=t;
    __syncthreads();
  }
  if(i<N) rp1[i]=s[threadIdx.x];
  if(threadIdx.x==255) bsums[blockIdx.x]=s[255];
}

__global__ void k_scan2(const int* __restrict__ bsums, int* __restrict__ boffs, int NB){
  __shared__ int s[512];
  int x=threadIdx.x;
  int v = (x<NB)? bsums[x] : 0;
  s[x]=v; __syncthreads();
  for(int off=1; off<512; off<<=1){
    int t=(x>=off)? s[x-off]:0; __syncthreads();
    s[x]+=t; __syncthreads();
  }
  if(x<NB) boffs[x]=s[x]-v;  // exclusive prefix
}

__global__ void k_scan3(int* __restrict__ row_ptr, const int* __restrict__ boffs,
                        const int* __restrict__ deg, float* __restrict__ dis, int N){
  int i = blockIdx.x*256+threadIdx.x;
  if(i<N){
    row_ptr[i+1] += boffs[blockIdx.x];
    int d = deg[i];
    dis[i] = (d>0)? rsqrtf((float)d) : 0.f;
    if(i==0) row_ptr[0]=0;
  }
}

__global__ void k_fill(const int* __restrict__ src, const int* __restrict__ dst,
                       const int* __restrict__ row_ptr, int* __restrict__ cursor,
                       int* __restrict__ csr_src, int E){
  int e = blockIdx.x*256+threadIdx.x;
  if(e<E){
    int d = dst[e];
    int pos = row_ptr[d] + atomicAdd(&cursor[d], 1);
    csr_src[pos]=src[e];
  }
}

// ---------------- single GEMM (skip branch): C[Mx64] = A[MxK] @ W[Kx64], bf16 out --------

template<int K, typename AT>
__global__ __launch_bounds__(256,2) void k_gemm(const AT* __restrict__ A, const float* __restrict__ W,
                                                bf16* __restrict__ Cb, int M){
  __shared__ float sAT[64][68];
  __shared__ float sW[64][64];
  const int t = threadIdx.x;
  const int m0 = blockIdx.x*64;
  const int tr = t>>4, tc = t&15;
  float acc[4][4] = {};
  for(int kc=0; kc<K/64; ++kc){
    #pragma unroll
    for(int it=0; it<4; ++it){
      int gli = t + it*256;
      int r = gli>>4, c4 = (gli&15)*4;
      int m = m0 + r;
      float v0=0,v1=0,v2=0,v3=0;
      if(m < M){
        const AT* ap = &A[(size_t)m*K + kc*64 + c4];
        v0=ldf(ap+0); v1=ldf(ap+1); v2=ldf(ap+2); v3=ldf(ap+3);
      }
      sAT[c4+0][r]=v0; sAT[c4+1][r]=v1; sAT[c4+2][r]=v2; sAT[c4+3][r]=v3;
    }
    #pragma unroll
    for(int it=0; it<4; ++it){
      int gli = t + it*256;
      int r = gli>>4, c4 = (gli&15)*4;
      float4 wv = *reinterpret_cast<const float4*>(&W[(size_t)(kc*64+r)*64 + c4]);
      *reinterpret_cast<float4*>(&sW[r][c4]) = wv;
    }
    __syncthreads();
    #pragma unroll 8
    for(int k=0;k<64;++k){
      const float4 av = *reinterpret_cast<const float4*>(&sAT[k][tr*4]);
      const float4 wv = *reinterpret_cast<const float4*>(&sW[k][tc*4]);
      acc[0][0]+=av.x*wv.x; acc[0][1]+=av.x*wv.y; acc[0][2]+=av.x*wv.z; acc[0][3]+=av.x*wv.w;
      acc[1][0]+=av.y*wv.x; acc[1][1]+=av.y*wv.y; acc[1][2]+=av.y*wv.z; acc[1][3]+=av.y*wv.w;
      acc[2][0]+=av.z*wv.x; acc[2][1]+=av.z*wv.y; acc[2][2]+=av.z*wv.z; acc[2][3]+=av.z*wv.w;
      acc[3][0]+=av.w*wv.x; acc[3][1]+=av.w*wv.y; acc[3][2]+=av.w*wv.z; acc[3][3]+=av.w*wv.w;
    }
    __syncthreads();
  }
  #pragma unroll
  for(int i=0;i<4;++i){
    int m = m0 + tr*4 + i;
    if(m<M){
      #pragma unroll
      for(int j=0;j<4;++j) Cb[(size_t)m*64 + tc*4+j] = f2b(acc[i][j]);
    }
  }
}

// ------------- fused dual-weight GEMM: stage A once, compute A@Wa and A@Wb --------------
// outA/outB bf16; if S0, also write outAs = dis[m]*valA (pre-scaled gather twin).
// LDS = 17.4KB(sAT) + 32.8KB(2 W tiles) = 50.2KB -> 3 blocks/CU.

template<int K, typename AT, bool S0>
__global__ __launch_bounds__(256,2) void k_gemm2(const AT* __restrict__ A,
    const float* __restrict__ Wa, const float* __restrict__ Wb,
    bf16* __restrict__ outA, bf16* __restrict__ outAs, bf16* __restrict__ outB,
    const float* __restrict__ dis, int M){
  __shared__ float sAT[64][68];
  __shared__ float sW[2][64][64];
  const int t = threadIdx.x;
  const int m0 = blockIdx.x*64;
  const int tr = t>>4, tc = t&15;
  float accA[4][4] = {}, accB[4][4] = {};
  for(int kc=0; kc<K/64; ++kc){
    #pragma unroll
    for(int it=0; it<4; ++it){
      int gli = t + it*256;
      int r = gli>>4, c4 = (gli&15)*4;
      int m = m0 + r;
      float v0=0,v1=0,v2=0,v3=0;
      if(m < M){
        const AT* ap = &A[(size_t)m*K + kc*64 + c4];
        v0=ldf(ap+0); v1=ldf(ap+1); v2=ldf(ap+2); v3=ldf(ap+3);
      }
      sAT[c4+0][r]=v0; sAT[c4+1][r]=v1; sAT[c4+2][r]=v2; sAT[c4+3][r]=v3;
    }
    #pragma unroll
    for(int it=0; it<8; ++it){
      int w = it>>2;
      int gli = t + (it&3)*256;
      int r = gli>>4, c4 = (gli&15)*4;
      const float* Wp = w ? Wb : Wa;
      float4 wv = *reinterpret_cast<const float4*>(&Wp[(size_t)(kc*64+r)*64 + c4]);
      *reinterpret_cast<float4*>(&sW[w][r][c4]) = wv;
    }
    __syncthreads();
    #pragma unroll 4
    for(int k=0;k<64;++k){
      const float4 av = *reinterpret_cast<const float4*>(&sAT[k][tr*4]);
      const float4 wa = *reinterpret_cast<const float4*>(&sW[0][k][tc*4]);
      const float4 wb = *reinterpret_cast<const float4*>(&sW[1][k][tc*4]);
      accA[0][0]+=av.x*wa.x; accA[0][1]+=av.x*wa.y; accA[0][2]+=av.x*wa.z; accA[0][3]+=av.x*wa.w;
      accA[1][0]+=av.y*wa.x; accA[1][1]+=av.y*wa.y; accA[1][2]+=av.y*wa.z; accA[1][3]+=av.y*wa.w;
      accA[2][0]+=av.z*wa.x; accA[2][1]+=av.z*wa.y; accA[2][2]+=av.z*wa.z; accA[2][3]+=av.z*wa.w;
      accA[3][0]+=av.w*wa.x; accA[3][1]+=av.w*wa.y; accA[3][2]+=av.w*wa.z; accA[3][3]+=av.w*wa.w;
      accB[0][0]+=av.x*wb.x; accB[0][1]+=av.x*wb.y; accB[0][2]+=av.x*wb.z; accB[0][3]+=av.x*wb.w;
      accB[1][0]+=av.y*wb.x; accB[1][1]+=av.y*wb.y; accB[1][2]+=av.y*wb.z; accB[1][3]+=av.y*wb.w;
      accB[2][0]+=av.z*wb.x; accB[2][1]+=av.z*wb.y; accB[2][2]+=av.z*wb.z; accB[2][3]+=av.z*wb.w;
      accB[3][0]+=av.w*wb.x; accB[3][1]+=av.w*wb.y; accB[3][2]+=av.w*wb.z; accB[3][3]+=av.w*wb.w;
    }
    __syncthreads();
  }
  #pragma unroll
  for(int i=0;i<4;++i){
    int m = m0 + tr*4 + i;
    if(m<M){
      float dm = S0 ? dis[m] : 0.f;
      #pragma unroll
      for(int j=0;j<4;++j){
        int c = tc*4+j;
        outA[(size_t)m*64+c] = f2b(accA[i][j]);
        if(S0) outAs[(size_t)m*64+c] = f2b(accA[i][j]*dm);
        outB[(size_t)m*64+c] = f2b(accB[i][j]);
      }
    }
  }
}

// mix GEMM: A = [h(64,bf16) | x(128,f32)] (M x 192), W = [Wmix0|Wmix1] (192 x (32+32))
// cols 0..31 -> Z0 (f32); cols 32..63 -> Z1s (bf16, PRE-SCALED by dis[m])
__global__ __launch_bounds__(256,2) void k_gemm_mix(const bf16* __restrict__ h, const float* __restrict__ x,
     const float* __restrict__ Wmix, float* __restrict__ Z0, bf16* __restrict__ Z1s,
     const float* __restrict__ dis, int M){
  __shared__ float sAT[64][68];
  __shared__ float sW[64][64];
  const int t=threadIdx.x, m0=blockIdx.x*64, tr=t>>4, tc=t&15;
  float acc[4][4]={};
  for(int kc=0;kc<3;++kc){
    #pragma unroll
    for(int it=0; it<4; ++it){
      int gli = t + it*256;
      int r = gli>>4, c4 = (gli&15)*4;
      int m = m0 + r;
      float v0=0,v1=0,v2=0,v3=0;
      if(m < M){
        if(kc==0){
          const bf16* hp=&h[(size_t)m*64 + c4];
          v0=b2f(hp[0]); v1=b2f(hp[1]); v2=b2f(hp[2]); v3=b2f(hp[3]);
        } else {
          float4 u = *reinterpret_cast<const float4*>(&x[(size_t)m*128 + (kc-1)*64 + c4]);
          v0=u.x; v1=u.y; v2=u.z; v3=u.w;
        }
      }
      sAT[c4+0][r]=v0; sAT[c4+1][r]=v1; sAT[c4+2][r]=v2; sAT[c4+3][r]=v3;
    }
    #pragma unroll
    for(int it=0; it<4; ++it){
      int gli = t + it*256;
      int r = gli>>4, c4 = (gli&15)*4;
      int gk = kc*64 + r;
      float4 wv = (c4<32) ? *reinterpret_cast<const float4*>(&Wmix[(size_t)gk*32 + c4])
                          : *reinterpret_cast<const float4*>(&Wmix[6144 + (size_t)gk*32 + (c4-32)]);
      *reinterpret_cast<float4*>(&sW[r][c4]) = wv;
    }
    __syncthreads();
    #pragma unroll 8
    for(int k=0;k<64;++k){
      const float4 av = *reinterpret_cast<const float4*>(&sAT[k][tr*4]);
      const float4 wv = *reinterpret_cast<const float4*>(&sW[k][tc*4]);
      acc[0][0]+=av.x*wv.x; acc[0][1]+=av.x*wv.y; acc[0][2]+=av.x*wv.z; acc[0][3]+=av.x*wv.w;
      acc[1][0]+=av.y*wv.x; acc[1][1]+=av.y*wv.y; acc[1][2]+=av.y*wv.z; acc[1][3]+=av.y*wv.w;
      acc[2][0]+=av.z*wv.x; acc[2][1]+=av.z*wv.y; acc[2][2]+=av.z*wv.z; acc[2][3]+=av.z*wv.w;
      acc[3][0]+=av.w*wv.x; acc[3][1]+=av.w*wv.y; acc[3][2]+=av.w*wv.z; acc[3][3]+=av.w*wv.w;
    }
    __syncthreads();
  }
  #pragma unroll
  for(int i=0;i<4;++i){
    int m=m0+tr*4+i;
    if(m<M){
      float dm = dis[m];
      #pragma unroll
      for(int j=0;j<4;++j){
        int c=tc*4+j;
        if(c<32) Z0[(size_t)m*32+c]=acc[i][j];
        else     Z1s[(size_t)m*32+(c-32)]=f2b(acc[i][j]*dm);
      }
    }
  }
}

// ---------------- sparse prop + Clenshaw combine ----------------
// a = dis[v] * sum_e BinS[src_e][f]   (BinS pre-scaled by dis[src]); L_hat t = -a
// MODE 0: r = Z - 2a          MODE 1: r = Z - 2a - Bsub
// MODE 2: r = relu(Z - a - Bsub + bias) + Zs + bias2
// MODE 3: r = Z - a + bias
template<int F, int MODE, bool SOUT, typename ZT, typename OT>
__global__ __launch_bounds__(256) void k_prop(const int* __restrict__ row_ptr, const int* __restrict__ csr_src,
    const float* __restrict__ dis, const bf16* __restrict__ BinS,
    const ZT* __restrict__ Z, const bf16* __restrict__ Bsub,
    const float* __restrict__ bias, const bf16* __restrict__ Zs, const float* __restrict__ bias2,
    OT* __restrict__ outN, bf16* __restrict__ outS, int N){
  constexpr int NPB = 256/F;
  int v = blockIdx.x*NPB + threadIdx.x/F;
  if(v>=N) return;
  int f = threadIdx.x % F;
  int e0=row_ptr[v], e1=row_ptr[v+1];
  float acc=0.f;
  int e=e0;
  for(; e+16<=e1; e+=16){
    int s[16];
    #pragma unroll
    for(int j=0;j<16;++j) s[j]=csr_src[e+j];
    float vv[16];
    #pragma unroll
    for(int j=0;j<16;++j) vv[j]=b2f(BinS[(unsigned)s[j]*F + f]);
    #pragma unroll
    for(int j=0;j<16;++j) acc+=vv[j];
  }
  if(e+8<=e1){
    int s[8];
    #pragma unroll
    for(int j=0;j<8;++j) s[j]=csr_src[e+j];
    float vv[8];
    #pragma unroll
    for(int j=0;j<8;++j) vv[j]=b2f(BinS[(unsigned)s[j]*F + f]);
    #pragma unroll
    for(int j=0;j<8;++j) acc+=vv[j];
    e+=8;
  }
  if(e<e1){
    #pragma unroll
    for(int j=0;j<8;++j){
      int idx=e+j;
      int s=csr_src[idx<e1 ? idx : e0];
      float vv=b2f(BinS[(unsigned)s*F + f]);
      acc += (idx<e1)? vv : 0.f;
    }
  }
  float dv = dis[v];
  float a = dv*acc;
  unsigned idx=(unsigned)v*F+f;
  float r;
  if(MODE==0)      r = ldf(&Z[idx]) - 2.f*a;
  else if(MODE==1) r = ldf(&Z[idx]) - 2.f*a - b2f(Bsub[idx]);
  else if(MODE==2){ float tv = ldf(&Z[idx]) - a - b2f(Bsub[idx]) + bias[f];
                    r = fmaxf(tv,0.f) + b2f(Zs[idx]) + bias2[f]; }
  else             r = ldf(&Z[idx]) - a + bias[f];
  stf(&outN[idx], r);
  if(SOUT) outS[idx] = f2b(dv*r);
}

// ---------------- host ----------------

extern "C" void kernel_launch(void* const* d_in, const int* in_sizes, int n_in,
                              void* d_out, int out_size, void* d_ws, size_t ws_size,
                              hipStream_t stream) {
  const int N = in_sizes[0]/128;     // 100000
  const int E = in_sizes[1]/2;       // 3200000

  const float* x    = (const float*)d_in[0];
  const int*   ei   = (const int*  )d_in[1];
  const float* W0   = (const float*)d_in[2];
  const float* b0   = (const float*)d_in[3];
  const float* Ws0  = (const float*)d_in[4];
  const float* bs0  = (const float*)d_in[5];
  const float* W1   = (const float*)d_in[6];
  const float* b1   = (const float*)d_in[7];
  const float* Ws1  = (const float*)d_in[8];
  const float* bs1  = (const float*)d_in[9];
  const float* W2   = (const float*)d_in[10];
  const float* b2   = (const float*)d_in[11];
  const float* Ws2  = (const float*)d_in[12];
  const float* bs2  = (const float*)d_in[13];
  const float* Wmix = (const float*)d_in[14];
  const float* bmix = (const float*)d_in[15];
  float* out = (float*)d_out;

  const int* src = ei;
  const int* dst = ei + E;

  // workspace carve (~155 MB, same as proven r6/r7 footprint)
  size_t off=0;
  char* ws=(char*)d_ws;
  auto alloc=[&](size_t bytes)->void*{ void* p = ws+off; off=(off+bytes+255)&~(size_t)255; return p; };
  int*   csr_src = (int*)  alloc((size_t)E*4);
  int*   row_ptr = (int*)  alloc((size_t)(N+1)*4);
  int*   cursor  = (int*)  alloc((size_t)N*4);
  int*   deg     = (int*)  alloc((size_t)N*4);
  float* dis     = (float*)alloc((size_t)N*4);
  int*   bsums   = (int*)  alloc(2048);
  int*   boffs   = (int*)  alloc(2048);
  bf16*  Za      = (bf16*) alloc((size_t)N*64*2);  // also reused as f32 N*32 for mix Z0
  bf16*  Zb      = (bf16*) alloc((size_t)N*64*2);
  bf16*  Zsb     = (bf16*) alloc((size_t)N*64*2);
  bf16*  P0n     = (bf16*) alloc((size_t)N*64*2);
  bf16*  P0s     = (bf16*) alloc((size_t)N*64*2);
  bf16*  P1n     = (bf16*) alloc((size_t)N*64*2);
  bf16*  P1s     = (bf16*) alloc((size_t)N*64*2);
  bf16*  P2n     = (bf16*) alloc((size_t)N*64*2);
  bf16*  P2s     = (bf16*) alloc((size_t)N*64*2);
  bf16*  hA      = (bf16*) alloc((size_t)N*64*2);
  bf16*  hB      = (bf16*) alloc((size_t)N*64*2);
  if(off > ws_size){
    fprintf(stderr, "kernel_launch: workspace too small: need %zu, have %zu\n", off, ws_size);
    return;
  }

  const int NB   = (N+255)/256;
  const int gE   = (E+255)/256;
  const int gG   = (N+63)/64;
  const int gP64 = (N+3)/4;
  const int gP32 = (N+7)/8;

  // graph prep
  hipMemsetAsync(deg, 0, (size_t)N*4, stream);
  hipMemsetAsync(cursor, 0, (size_t)N*4, stream);
  k_count<<<gE,256,0,stream>>>(dst, deg, E);
  k_scan1<<<NB,256,0,stream>>>(deg, row_ptr+1, bsums, N);
  k_scan2<<<1,512,0,stream>>>(bsums, boffs, NB);
  k_scan3<<<NB,256,0,stream>>>(row_ptr, boffs, deg, dis, N);
  k_fill<<<gE,256,0,stream>>>(src, dst, row_ptr, cursor, csr_src, E);

  // ChebConv layer via Clenshaw, fused dual-weight GEMMs, 2 live Z slots:
  // G1:{W5->(P0n,P0s), W4->Za}  pB4  G2:{W3->Za', W2->Zb}  pB3  pB2  G3:{W1->Za'', W0->Zb'}  pB1  pH
  auto LAYER=[&](auto hin, int K, const float* W, const float* b, const float* Ws, const float* bs, bf16* hout){
    using AT = std::remove_const_t<std::remove_pointer_t<decltype(hin)>>;
    size_t WK=(size_t)K*64;
    if(K==128){
      k_gemm<128,AT><<<gG,256,0,stream>>>(hin, Ws, Zsb, N);
      k_gemm2<128,AT,true ><<<gG,256,0,stream>>>(hin, W+5*WK, W+4*WK, P0n, P0s, Za, dis, N);
    } else {
      k_gemm<64,AT><<<gG,256,0,stream>>>(hin, Ws, Zsb, N);
      k_gemm2<64,AT,true ><<<gG,256,0,stream>>>(hin, W+5*WK, W+4*WK, P0n, P0s, Za, dis, N);
    }
    k_prop<64,0,true,bf16,bf16><<<gP64,256,0,stream>>>(row_ptr,csr_src,dis,P0s,Za,nullptr,nullptr,nullptr,nullptr,P1n,P1s,N); // B4
    if(K==128) k_gemm2<128,AT,false><<<gG,256,0,stream>>>(hin, W+3*WK, W+2*WK, Za, nullptr, Zb, dis, N);
    else       k_gemm2<64 ,AT,false><<<gG,256,0,stream>>>(hin, W+3*WK, W+2*WK, Za, nullptr, Zb, dis, N);
    k_prop<64,1,true,bf16,bf16><<<gP64,256,0,stream>>>(row_ptr,csr_src,dis,P1s,Za,P0n,nullptr,nullptr,nullptr,P2n,P2s,N);     // B3
    k_prop<64,1,true,bf16,bf16><<<gP64,256,0,stream>>>(row_ptr,csr_src,dis,P2s,Zb,P1n,nullptr,nullptr,nullptr,P0n,P0s,N);     // B2
    if(K==128) k_gemm2<128,AT,false><<<gG,256,0,stream>>>(hin, W+1*WK, W+0*WK, Za, nullptr, Zb, dis, N);
    else       k_gemm2<64 ,AT,false><<<gG,256,0,stream>>>(hin, W+1*WK, W+0*WK, Za, nullptr, Zb, dis, N);
    k_prop<64,1,true,bf16,bf16><<<gP64,256,0,stream>>>(row_ptr,csr_src,dis,P0s,Za,P2n,nullptr,nullptr,nullptr,P1n,P1s,N);     // B1
    k_prop<64,2,false,bf16,bf16><<<gP64,256,0,stream>>>(row_ptr,csr_src,dis,P1s,Zb,P0n,b,Zsb,bs,hout,nullptr,N);              // h'
  };

  LAYER(x , 128, W0, b0, Ws0, bs0, hA);
  LAYER(hA,  64, W1, b1, Ws1, bs1, hB);
  LAYER(hB,  64, W2, b2, Ws2, bs2, hA);

  // mix head: out = Z0m + L_hat(Z1m) + bmix,  hcat = [hA | x]
  float* Zmixf = (float*)Za;   // N*32 f32 == N*64 bf16 bytes; Za free here
  k_gemm_mix<<<gG,256,0,stream>>>(hA, x, Wmix, Zmixf, P0s, dis, N);
  k_prop<32,3,false,float,float><<<gP32,256,0,stream>>>(row_ptr,csr_src,dis,P0s,Zmixf,nullptr,bmix,nullptr,nullptr,out,nullptr,N);
}

// Round 9
// 1808.924 us; speedup vs baseline: 2.1652x; 1.0015x over previous
//
#include <hip/hip_runtime.h>
#include <hip/hip_bf16.h>
#include <cstdio>
#include <cstdint>
#include <type_traits>

typedef __hip_bfloat16 bf16;

static __device__ __forceinline__ float b2f(bf16 v){ return __bfloat162float(v); }
static __device__ __forceinline__ bf16  f2b(float v){ return __float2bfloat16(v); }
static __device__ __forceinline__ float ldf(const float* p){ return *p; }
static __device__ __forceinline__ float ldf(const bf16* p){ return b2f(*p); }
static __device__ __forceinline__ void  stf(float* p, float v){ *p = v; }
static __device__ __forceinline__ void  stf(bf16*  p, float v){ *p = f2b(v); }

// ---------------- graph prep ----------------

__global__ void k_count(const int* __restrict__ dst, int* __restrict__ deg, int E){
  int i = blockIdx.x*256 + threadIdx.x;
  int e = i*2;
  if(e+1<E){
    int2 d2 = *reinterpret_cast<const int2*>(&dst[e]);
    atomicAdd(&deg[d2.x], 1);
    atomicAdd(&deg[d2.y], 1);
  } else if(e<E){
    atomicAdd(&deg[dst[e]], 1);
  }
}

__global__ void k_scan1(const int* __restrict__ deg, int* __restrict__ rp1, int* __restrict__ bsums, int N){
  __shared__ int s[256];
  int i = blockIdx.x*256 + threadIdx.x;
  int v = (i<N)? deg[i] : 0;
  s[threadIdx.x]=v; __syncthreads();
  for(int off=1; off<256; off<<=1){
    int t = (threadIdx.x>=off)? s[threadIdx.x-off] : 0;
    __syncthreads();
    s[threadIdx.x]+=t;
    __syncthreads();
  }
  if(i<N) rp1[i]=s[threadIdx.x];
  if(threadIdx.x==255) bsums[blockIdx.x]=s[255];
}

__global__ void k_scan2(const int* __restrict__ bsums, int* __restrict__ boffs, int NB){
  __shared__ int s[512];
  int x=threadIdx.x;
  int v = (x<NB)? bsums[x] : 0;
  s[x]=v; __syncthreads();
  for(int off=1; off<512; off<<=1){
    int t=(x>=off)? s[x-off]:0; __syncthreads();
    s[x]+=t; __syncthreads();
  }
  if(x<NB) boffs[x]=s[x]-v;  // exclusive prefix
}

__global__ void k_scan3(int* __restrict__ row_ptr, const int* __restrict__ boffs,
                        const int* __restrict__ deg, float* __restrict__ dis, float* __restrict__ dinv, int N){
  int i = blockIdx.x*256+threadIdx.x;
  if(i<N){
    row_ptr[i+1] += boffs[blockIdx.x];
    int d = deg[i];
    dis[i]  = (d>0)? rsqrtf((float)d) : 0.f;
    dinv[i] = (d>0)? sqrtf((float)d)  : 0.f;   // 1/dis
    if(i==0) row_ptr[0]=0;
  }
}

// CSR fill: deg doubles as countdown cursor (slots filled in reverse).
__global__ void k_fill(const int* __restrict__ src, const int* __restrict__ dst,
                       const int* __restrict__ row_ptr, int* __restrict__ deg,
                       int* __restrict__ csr_src, int E){
  int i = blockIdx.x*256+threadIdx.x;
  int e = i*2;
  if(e+1<E){
    int2 s2 = *reinterpret_cast<const int2*>(&src[e]);
    int2 d2 = *reinterpret_cast<const int2*>(&dst[e]);
    int p0 = row_ptr[d2.x] + atomicAdd(&deg[d2.x],-1) - 1;
    csr_src[p0] = s2.x;
    int p1 = row_ptr[d2.y] + atomicAdd(&deg[d2.y],-1) - 1;
    csr_src[p1] = s2.y;
  } else if(e<E){
    int d = dst[e];
    int pos = row_ptr[d] + atomicAdd(&deg[d],-1) - 1;
    csr_src[pos] = src[e];
  }
}

// ---------------- single GEMM (skip branch): C[Mx64] = A[MxK] @ W[Kx64], bf16 out --------

template<int K, typename AT>
__global__ __launch_bounds__(256,2) void k_gemm(const AT* __restrict__ A, const float* __restrict__ W,
                                                bf16* __restrict__ Cb, int M){
  __shared__ float sAT[64][68];
  __shared__ float sW[64][64];
  const int t = threadIdx.x;
  const int m0 = blockIdx.x*64;
  const int tr = t>>4, tc = t&15;
  float acc[4][4] = {};
  for(int kc=0; kc<K/64; ++kc){
    #pragma unroll
    for(int it=0; it<4; ++it){
      int gli = t + it*256;
      int r = gli>>4, c4 = (gli&15)*4;
      int m = m0 + r;
      float v0=0,v1=0,v2=0,v3=0;
      if(m < M){
        const AT* ap = &A[(size_t)m*K + kc*64 + c4];
        v0=ldf(ap+0); v1=ldf(ap+1); v2=ldf(ap+2); v3=ldf(ap+3);
      }
      sAT[c4+0][r]=v0; sAT[c4+1][r]=v1; sAT[c4+2][r]=v2; sAT[c4+3][r]=v3;
    }
    #pragma unroll
    for(int it=0; it<4; ++it){
      int gli = t + it*256;
      int r = gli>>4, c4 = (gli&15)*4;
      float4 wv = *reinterpret_cast<const float4*>(&W[(size_t)(kc*64+r)*64 + c4]);
      *reinterpret_cast<float4*>(&sW[r][c4]) = wv;
    }
    __syncthreads();
    #pragma unroll 8
    for(int k=0;k<64;++k){
      const float4 av = *reinterpret_cast<const float4*>(&sAT[k][tr*4]);
      const float4 wv = *reinterpret_cast<const float4*>(&sW[k][tc*4]);
      acc[0][0]+=av.x*wv.x; acc[0][1]+=av.x*wv.y; acc[0][2]+=av.x*wv.z; acc[0][3]+=av.x*wv.w;
      acc[1][0]+=av.y*wv.x; acc[1][1]+=av.y*wv.y; acc[1][2]+=av.y*wv.z; acc[1][3]+=av.y*wv.w;
      acc[2][0]+=av.z*wv.x; acc[2][1]+=av.z*wv.y; acc[2][2]+=av.z*wv.z; acc[2][3]+=av.z*wv.w;
      acc[3][0]+=av.w*wv.x; acc[3][1]+=av.w*wv.y; acc[3][2]+=av.w*wv.z; acc[3][3]+=av.w*wv.w;
    }
    __syncthreads();
  }
  #pragma unroll
  for(int i=0;i<4;++i){
    int m = m0 + tr*4 + i;
    if(m<M){
      #pragma unroll
      for(int j=0;j<4;++j) Cb[(size_t)m*64 + tc*4+j] = f2b(acc[i][j]);
    }
  }
}

// ------------- fused dual-weight GEMM: stage A once, compute A@Wa and A@Wb --------------
// S0=true : first output written ONLY pre-scaled (outAs = dis[m]*valA, gather twin)
// S0=false: first output written normal (outA)

template<int K, typename AT, bool S0>
__global__ __launch_bounds__(256,2) void k_gemm2(const AT* __restrict__ A,
    const float* __restrict__ Wa, const float* __restrict__ Wb,
    bf16* __restrict__ outA, bf16* __restrict__ outAs, bf16* __restrict__ outB,
    const float* __restrict__ dis, int M){
  __shared__ float sAT[64][68];
  __shared__ float sW[2][64][64];
  const int t = threadIdx.x;
  const int m0 = blockIdx.x*64;
  const int tr = t>>4, tc = t&15;
  float accA[4][4] = {}, accB[4][4] = {};
  for(int kc=0; kc<K/64; ++kc){
    #pragma unroll
    for(int it=0; it<4; ++it){
      int gli = t + it*256;
      int r = gli>>4, c4 = (gli&15)*4;
      int m = m0 + r;
      float v0=0,v1=0,v2=0,v3=0;
      if(m < M){
        const AT* ap = &A[(size_t)m*K + kc*64 + c4];
        v0=ldf(ap+0); v1=ldf(ap+1); v2=ldf(ap+2); v3=ldf(ap+3);
      }
      sAT[c4+0][r]=v0; sAT[c4+1][r]=v1; sAT[c4+2][r]=v2; sAT[c4+3][r]=v3;
    }
    #pragma unroll
    for(int it=0; it<8; ++it){
      int w = it>>2;
      int gli = t + (it&3)*256;
      int r = gli>>4, c4 = (gli&15)*4;
      const float* Wp = w ? Wb : Wa;
      float4 wv = *reinterpret_cast<const float4*>(&Wp[(size_t)(kc*64+r)*64 + c4]);
      *reinterpret_cast<float4*>(&sW[w][r][c4]) = wv;
    }
    __syncthreads();
    #pragma unroll 4
    for(int k=0;k<64;++k){
      const float4 av = *reinterpret_cast<const float4*>(&sAT[k][tr*4]);
      const float4 wa = *reinterpret_cast<const float4*>(&sW[0][k][tc*4]);
      const float4 wb = *reinterpret_cast<const float4*>(&sW[1][k][tc*4]);
      accA[0][0]+=av.x*wa.x; accA[0][1]+=av.x*wa.y; accA[0][2]+=av.x*wa.z; accA[0][3]+=av.x*wa.w;
      accA[1][0]+=av.y*wa.x; accA[1][1]+=av.y*wa.y; accA[1][2]+=av.y*wa.z; accA[1][3]+=av.y*wa.w;
      accA[2][0]+=av.z*wa.x; accA[2][1]+=av.z*wa.y; accA[2][2]+=av.z*wa.z; accA[2][3]+=av.z*wa.w;
      accA[3][0]+=av.w*wa.x; accA[3][1]+=av.w*wa.y; accA[3][2]+=av.w*wa.z; accA[3][3]+=av.w*wa.w;
      accB[0][0]+=av.x*wb.x; accB[0][1]+=av.x*wb.y; accB[0][2]+=av.x*wb.z; accB[0][3]+=av.x*wb.w;
      accB[1][0]+=av.y*wb.x; accB[1][1]+=av.y*wb.y; accB[1][2]+=av.y*wb.z; accB[1][3]+=av.y*wb.w;
      accB[2][0]+=av.z*wb.x; accB[2][1]+=av.z*wb.y; accB[2][2]+=av.z*wb.z; accB[2][3]+=av.z*wb.w;
      accB[3][0]+=av.w*wb.x; accB[3][1]+=av.w*wb.y; accB[3][2]+=av.w*wb.z; accB[3][3]+=av.w*wb.w;
    }
    __syncthreads();
  }
  #pragma unroll
  for(int i=0;i<4;++i){
    int m = m0 + tr*4 + i;
    if(m<M){
      float dm = S0 ? dis[m] : 0.f;
      #pragma unroll
      for(int j=0;j<4;++j){
        int c = tc*4+j;
        if(S0) outAs[(size_t)m*64+c] = f2b(accA[i][j]*dm);
        else   outA [(size_t)m*64+c] = f2b(accA[i][j]);
        outB[(size_t)m*64+c] = f2b(accB[i][j]);
      }
    }
  }
}

// mix GEMM: A = [h(64,bf16) | x(128,f32)] (M x 192), W = [Wmix0|Wmix1] (192 x (32+32))
// cols 0..31 -> Z0 (f32); cols 32..63 -> Z1s (bf16, PRE-SCALED by dis[m])
__global__ __launch_bounds__(256,2) void k_gemm_mix(const bf16* __restrict__ h, const float* __restrict__ x,
     const float* __restrict__ Wmix, float* __restrict__ Z0, bf16* __restrict__ Z1s,
     const float* __restrict__ dis, int M){
  __shared__ float sAT[64][68];
  __shared__ float sW[64][64];
  const int t=threadIdx.x, m0=blockIdx.x*64, tr=t>>4, tc=t&15;
  float acc[4][4]={};
  for(int kc=0;kc<3;++kc){
    #pragma unroll
    for(int it=0; it<4; ++it){
      int gli = t + it*256;
      int r = gli>>4, c4 = (gli&15)*4;
      int m = m0 + r;
      float v0=0,v1=0,v2=0,v3=0;
      if(m < M){
        if(kc==0){
          const bf16* hp=&h[(size_t)m*64 + c4];
          v0=b2f(hp[0]); v1=b2f(hp[1]); v2=b2f(hp[2]); v3=b2f(hp[3]);
        } else {
          float4 u = *reinterpret_cast<const float4*>(&x[(size_t)m*128 + (kc-1)*64 + c4]);
          v0=u.x; v1=u.y; v2=u.z; v3=u.w;
        }
      }
      sAT[c4+0][r]=v0; sAT[c4+1][r]=v1; sAT[c4+2][r]=v2; sAT[c4+3][r]=v3;
    }
    #pragma unroll
    for(int it=0; it<4; ++it){
      int gli = t + it*256;
      int r = gli>>4, c4 = (gli&15)*4;
      int gk = kc*64 + r;
      float4 wv = (c4<32) ? *reinterpret_cast<const float4*>(&Wmix[(size_t)gk*32 + c4])
                          : *reinterpret_cast<const float4*>(&Wmix[6144 + (size_t)gk*32 + (c4-32)]);
      *reinterpret_cast<float4*>(&sW[r][c4]) = wv;
    }
    __syncthreads();
    #pragma unroll 8
    for(int k=0;k<64;++k){
      const float4 av = *reinterpret_cast<const float4*>(&sAT[k][tr*4]);
      const float4 wv = *reinterpret_cast<const float4*>(&sW[k][tc*4]);
      acc[0][0]+=av.x*wv.x; acc[0][1]+=av.x*wv.y; acc[0][2]+=av.x*wv.z; acc[0][3]+=av.x*wv.w;
      acc[1][0]+=av.y*wv.x; acc[1][1]+=av.y*wv.y; acc[1][2]+=av.y*wv.z; acc[1][3]+=av.y*wv.w;
      acc[2][0]+=av.z*wv.x; acc[2][1]+=av.z*wv.y; acc[2][2]+=av.z*wv.z; acc[2][3]+=av.z*wv.w;
      acc[3][0]+=av.w*wv.x; acc[3][1]+=av.w*wv.y; acc[3][2]+=av.w*wv.z; acc[3][3]+=av.w*wv.w;
    }
    __syncthreads();
  }
  #pragma unroll
  for(int i=0;i<4;++i){
    int m=m0+tr*4+i;
    if(m<M){
      float dm = dis[m];
      #pragma unroll
      for(int j=0;j<4;++j){
        int c=tc*4+j;
        if(c<32) Z0[(size_t)m*32+c]=acc[i][j];
        else     Z1s[(size_t)m*32+(c-32)]=f2b(acc[i][j]*dm);
      }
    }
  }
}

// ---------------- sparse prop + Clenshaw combine ----------------
// a = dis[v] * sum_e BinS[src_e][f]   (BinS pre-scaled by dis[src]); L_hat t = -a
// Bsub recovered from its SCALED buffer: Bsub = BsubS[idx]*dinv[v] (wave-uniform mul)
// MODE 0: r = Z - 2a                         -> store SCALED (dis[v]*r)
// MODE 1: r = Z - 2a - BsubS*dinv            -> store SCALED
// MODE 2: r = relu(Z - a - BsubS*dinv + bias) + Zs + bias2 -> store normal bf16
// MODE 3: r = Z - a + bias                   -> store normal f32
template<int F, int MODE, typename ZT, typename OT>
__global__ __launch_bounds__(256) void k_prop(const int* __restrict__ row_ptr, const int* __restrict__ csr_src,
    const float* __restrict__ dis, const float* __restrict__ dinv, const bf16* __restrict__ BinS,
    const ZT* __restrict__ Z, const bf16* __restrict__ BsubS,
    const float* __restrict__ bias, const bf16* __restrict__ Zs, const float* __restrict__ bias2,
    OT* __restrict__ out, int N){
  constexpr int NPB = 256/F;
  int v = blockIdx.x*NPB + threadIdx.x/F;
  if(v>=N) return;
  int f = threadIdx.x % F;
  int e0=row_ptr[v], e1=row_ptr[v+1];
  float acc=0.f;
  int e=e0;
  for(; e+16<=e1; e+=16){
    int s[16];
    #pragma unroll
    for(int j=0;j<16;++j) s[j]=csr_src[e+j];
    float vv[16];
    #pragma unroll
    for(int j=0;j<16;++j) vv[j]=b2f(BinS[(unsigned)s[j]*F + f]);
    #pragma unroll
    for(int j=0;j<16;++j) acc+=vv[j];
  }
  if(e+8<=e1){
    int s[8];
    #pragma unroll
    for(int j=0;j<8;++j) s[j]=csr_src[e+j];
    float vv[8];
    #pragma unroll
    for(int j=0;j<8;++j) vv[j]=b2f(BinS[(unsigned)s[j]*F + f]);
    #pragma unroll
    for(int j=0;j<8;++j) acc+=vv[j];
    e+=8;
  }
  if(e<e1){
    #pragma unroll
    for(int j=0;j<8;++j){
      int idx=e+j;
      int s=csr_src[idx<e1 ? idx : e0];
      float vv=b2f(BinS[(unsigned)s*F + f]);
      acc += (idx<e1)? vv : 0.f;
    }
  }
  float dv = dis[v];
  float di = dinv[v];
  float a = dv*acc;
  unsigned idx=(unsigned)v*F+f;
  float r;
  if(MODE==0)      r = ldf(&Z[idx]) - 2.f*a;
  else if(MODE==1) r = ldf(&Z[idx]) - 2.f*a - b2f(BsubS[idx])*di;
  else if(MODE==2){ float tv = ldf(&Z[idx]) - a - b2f(BsubS[idx])*di + bias[f];
                    r = fmaxf(tv,0.f) + b2f(Zs[idx]) + bias2[f]; }
  else             r = ldf(&Z[idx]) - a + bias[f];
  if(MODE<=1) stf(&out[idx], dv*r);   // scaled store (single stream)
  else        stf(&out[idx], r);
}

// ---------------- host ----------------

extern "C" void kernel_launch(void* const* d_in, const int* in_sizes, int n_in,
                              void* d_out, int out_size, void* d_ws, size_t ws_size,
                              hipStream_t stream) {
  const int N = in_sizes[0]/128;     // 100000
  const int E = in_sizes[1]/2;       // 3200000

  const float* x    = (const float*)d_in[0];
  const int*   ei   = (const int*  )d_in[1];
  const float* W0   = (const float*)d_in[2];
  const float* b0   = (const float*)d_in[3];
  const float* Ws0  = (const float*)d_in[4];
  const float* bs0  = (const float*)d_in[5];
  const float* W1   = (const float*)d_in[6];
  const float* b1   = (const float*)d_in[7];
  const float* Ws1  = (const float*)d_in[8];
  const float* bs1  = (const float*)d_in[9];
  const float* W2   = (const float*)d_in[10];
  const float* b2   = (const float*)d_in[11];
  const float* Ws2  = (const float*)d_in[12];
  const float* bs2  = (const float*)d_in[13];
  const float* Wmix = (const float*)d_in[14];
  const float* bmix = (const float*)d_in[15];
  float* out = (float*)d_out;

  const int* src = ei;
  const int* dst = ei + E;

  // workspace carve (~117 MB)
  size_t off=0;
  char* ws=(char*)d_ws;
  auto alloc=[&](size_t bytes)->void*{ void* p = ws+off; off=(off+bytes+255)&~(size_t)255; return p; };
  int*   csr_src = (int*)  alloc((size_t)E*4);
  int*   row_ptr = (int*)  alloc((size_t)(N+1)*4);
  int*   deg     = (int*)  alloc((size_t)N*4);
  float* dis     = (float*)alloc((size_t)N*4);
  float* dinv    = (float*)alloc((size_t)N*4);
  int*   bsums   = (int*)  alloc(2048);
  int*   boffs   = (int*)  alloc(2048);
  bf16*  Za      = (bf16*) alloc((size_t)N*64*2);  // reused as f32 N*32 for mix Z0
  bf16*  Zb      = (bf16*) alloc((size_t)N*64*2);
  bf16*  Zsb     = (bf16*) alloc((size_t)N*64*2);
  bf16*  P0s     = (bf16*) alloc((size_t)N*64*2);
  bf16*  P1s     = (bf16*) alloc((size_t)N*64*2);
  bf16*  P2s     = (bf16*) alloc((size_t)N*64*2);
  bf16*  hA      = (bf16*) alloc((size_t)N*64*2);
  bf16*  hB      = (bf16*) alloc((size_t)N*64*2);
  if(off > ws_size){
    fprintf(stderr, "kernel_launch: workspace too small: need %zu, have %zu\n", off, ws_size);
    return;
  }

  const int NB   = (N+255)/256;
  const int gE2  = (E/2+256)/256;   // 2 edges/thread
  const int gG   = (N+63)/64;
  const int gP64 = (N+3)/4;
  const int gP32 = (N+7)/8;

  // graph prep
  hipMemsetAsync(deg, 0, (size_t)N*4, stream);
  k_count<<<gE2,256,0,stream>>>(dst, deg, E);
  k_scan1<<<NB,256,0,stream>>>(deg, row_ptr+1, bsums, N);
  k_scan2<<<1,512,0,stream>>>(bsums, boffs, NB);
  k_scan3<<<NB,256,0,stream>>>(row_ptr, boffs, deg, dis, dinv, N);
  k_fill<<<gE2,256,0,stream>>>(src, dst, row_ptr, deg, csr_src, E);

  // ChebConv layer via Clenshaw, SCALED-ONLY intermediate buffers:
  // B5s=dis*Z5; B4s=dis*(Z4-2a(B5)); ... Bsub recovered as Ps*dinv in-consumer.
  auto LAYER=[&](auto hin, int K, const float* W, const float* b, const float* Ws, const float* bs, bf16* hout){
    using AT = std::remove_const_t<std::remove_pointer_t<decltype(hin)>>;
    size_t WK=(size_t)K*64;
    if(K==128){
      k_gemm<128,AT><<<gG,256,0,stream>>>(hin, Ws, Zsb, N);
      k_gemm2<128,AT,true ><<<gG,256,0,stream>>>(hin, W+5*WK, W+4*WK, nullptr, P0s, Za, dis, N);
    } else {
      k_gemm<64,AT><<<gG,256,0,stream>>>(hin, Ws, Zsb, N);
      k_gemm2<64,AT,true ><<<gG,256,0,stream>>>(hin, W+5*WK, W+4*WK, nullptr, P0s, Za, dis, N);
    }
    k_prop<64,0,bf16,bf16><<<gP64,256,0,stream>>>(row_ptr,csr_src,dis,dinv,P0s,Za,nullptr,nullptr,nullptr,nullptr,P1s,N); // B4
    if(K==128) k_gemm2<128,AT,false><<<gG,256,0,stream>>>(hin, W+3*WK, W+2*WK, Za, nullptr, Zb, dis, N);
    else       k_gemm2<64 ,AT,false><<<gG,256,0,stream>>>(hin, W+3*WK, W+2*WK, Za, nullptr, Zb, dis, N);
    k_prop<64,1,bf16,bf16><<<gP64,256,0,stream>>>(row_ptr,csr_src,dis,dinv,P1s,Za,P0s,nullptr,nullptr,nullptr,P2s,N);     // B3
    k_prop<64,1,bf16,bf16><<<gP64,256,0,stream>>>(row_ptr,csr_src,dis,dinv,P2s,Zb,P1s,nullptr,nullptr,nullptr,P0s,N);     // B2
    if(K==128) k_gemm2<128,AT,false><<<gG,256,0,stream>>>(hin, W+1*WK, W+0*WK, Za, nullptr, Zb, dis, N);
    else       k_gemm2<64 ,AT,false><<<gG,256,0,stream>>>(hin, W+1*WK, W+0*WK, Za, nullptr, Zb, dis, N);
    k_prop<64,1,bf16,bf16><<<gP64,256,0,stream>>>(row_ptr,csr_src,dis,dinv,P0s,Za,P2s,nullptr,nullptr,nullptr,P1s,N);     // B1
    k_prop<64,2,bf16,bf16><<<gP64,256,0,stream>>>(row_ptr,csr_src,dis,dinv,P1s,Zb,P0s,b,Zsb,bs,hout,N);                   // h'
  };

  LAYER(x , 128, W0, b0, Ws0, bs0, hA);
  LAYER(hA,  64, W1, b1, Ws1, bs1, hB);
  LAYER(hB,  64, W2, b2, Ws2, bs2, hA);

  // mix head: out = Z0m + L_hat(Z1m) + bmix,  hcat = [hA | x]
  float* Zmixf = (float*)Za;   // N*32 f32 == N*64 bf16 bytes; Za free here
  k_gemm_mix<<<gG,256,0,stream>>>(hA, x, Wmix, Zmixf, P0s, dis, N);
  k_prop<32,3,float,float><<<gP32,256,0,stream>>>(row_ptr,csr_src,dis,dinv,P0s,Zmixf,nullptr,bmix,nullptr,nullptr,out,N);
}

// Round 10
// 1726.957 us; speedup vs baseline: 2.2680x; 1.0475x over previous
//
#include <hip/hip_runtime.h>
#include <hip/hip_bf16.h>
#include <cstdio>
#include <cstdint>

typedef __hip_bfloat16 bf16;

static __device__ __forceinline__ float b2f(bf16 v){ return __bfloat162float(v); }
static __device__ __forceinline__ bf16  f2b(float v){ return __float2bfloat16(v); }
static __device__ __forceinline__ float ldf(const float* p){ return *p; }
static __device__ __forceinline__ float ldf(const bf16* p){ return b2f(*p); }
static __device__ __forceinline__ void  stf(float* p, float v){ *p = v; }
static __device__ __forceinline__ void  stf(bf16*  p, float v){ *p = f2b(v); }

// ---------------- graph prep ----------------

__global__ void k_count(const int* __restrict__ dst, int* __restrict__ deg, int E){
  int e = blockIdx.x*256 + threadIdx.x;
  if(e<E) atomicAdd(&deg[dst[e]], 1);
}

__global__ void k_scan1(const int* __restrict__ deg, int* __restrict__ rp1, int* __restrict__ bsums, int N){
  __shared__ int s[256];
  int i = blockIdx.x*256 + threadIdx.x;
  int v = (i<N)? deg[i] : 0;
  s[threadIdx.x]=v; __syncthreads();
  for(int off=1; off<256; off<<=1){
    int t = (threadIdx.x>=off)? s[threadIdx.x-off] : 0;
    __syncthreads();
    s[threadIdx.x]+=t;
    __syncthreads();
  }
  if(i<N) rp1[i]=s[threadIdx.x];
  if(threadIdx.x==255) bsums[blockIdx.x]=s[255];
}

__global__ void k_scan2(const int* __restrict__ bsums, int* __restrict__ boffs, int NB){
  __shared__ int s[512];
  int x=threadIdx.x;
  int v = (x<NB)? bsums[x] : 0;
  s[x]=v; __syncthreads();
  for(int off=1; off<512; off<<=1){
    int t=(x>=off)? s[x-off]:0; __syncthreads();
    s[x]+=t; __syncthreads();
  }
  if(x<NB) boffs[x]=s[x]-v;  // exclusive prefix
}

__global__ void k_scan3(int* __restrict__ row_ptr, const int* __restrict__ boffs,
                        const int* __restrict__ deg, float* __restrict__ dis, float* __restrict__ dinv, int N){
  int i = blockIdx.x*256+threadIdx.x;
  if(i<N){
    row_ptr[i+1] += boffs[blockIdx.x];
    int d = deg[i];
    dis[i]  = (d>0)? rsqrtf((float)d) : 0.f;
    dinv[i] = (d>0)? sqrtf((float)d)  : 0.f;   // 1/dis (deg-0 nodes: none in this graph, P~e^-32)
    if(i==0) row_ptr[0]=0;
  }
}

// CSR fill: 1 edge/thread (r9: 2/thread regressed +20%); deg doubles as countdown cursor.
__global__ void k_fill(const int* __restrict__ src, const int* __restrict__ dst,
                       const int* __restrict__ row_ptr, int* __restrict__ deg,
                       int* __restrict__ csr_src, int E){
  int e = blockIdx.x*256+threadIdx.x;
  if(e<E){
    int d = dst[e];
    int pos = row_ptr[d] + atomicAdd(&deg[d],-1) - 1;
    csr_src[pos] = src[e];
  }
}

// -------- mega GEMM: 7 weight matrices against one A, single dispatch --------
// Wl = {Ws, W5, W4, W3, W2, W1, W0};  Ol = {Zsb, P0s(SCALED by dis[m]), Z4, Z3, Z2, Z1, Z0}
// 4 phases x {stage 2 W tiles, dual-accumulate, write 2 outputs}; A staged once (K=64)
// or per phase-chunk (K=128). LDS = 17.4K(sAT) + 32.8K(2 W) = 50.2 KB -> 3 blocks/CU.

template<int K, typename AT>
__global__ __launch_bounds__(256,2) void k_gemm7(const AT* __restrict__ A,
    const float* __restrict__ Wq0, const float* __restrict__ Wq1, const float* __restrict__ Wq2,
    const float* __restrict__ Wq3, const float* __restrict__ Wq4, const float* __restrict__ Wq5,
    const float* __restrict__ Wq6,
    bf16* __restrict__ O0, bf16* __restrict__ O1, bf16* __restrict__ O2, bf16* __restrict__ O3,
    bf16* __restrict__ O4, bf16* __restrict__ O5, bf16* __restrict__ O6,
    const float* __restrict__ dis, int M){
  __shared__ float sAT[64][68];
  __shared__ float sW[2][64][64];
  const int t = threadIdx.x;
  const int m0 = blockIdx.x*64;
  const int tr = t>>4, tc = t&15;
  const float* Wl[7] = {Wq0,Wq1,Wq2,Wq3,Wq4,Wq5,Wq6};
  bf16*       Ol[7] = {O0,O1,O2,O3,O4,O5,O6};

  auto stageA=[&](int kc){
    #pragma unroll
    for(int it=0; it<4; ++it){
      int gli = t + it*256;
      int r = gli>>4, c4 = (gli&15)*4;
      int m = m0 + r;
      float v0=0,v1=0,v2=0,v3=0;
      if(m < M){
        const AT* ap = &A[(size_t)m*K + kc*64 + c4];
        v0=ldf(ap+0); v1=ldf(ap+1); v2=ldf(ap+2); v3=ldf(ap+3);
      }
      sAT[c4+0][r]=v0; sAT[c4+1][r]=v1; sAT[c4+2][r]=v2; sAT[c4+3][r]=v3;
    }
  };
  auto stageW=[&](const float* Wp, int slot, int kc){
    #pragma unroll
    for(int it=0; it<4; ++it){
      int gli = t + it*256;
      int r = gli>>4, c4 = (gli&15)*4;
      float4 wv = *reinterpret_cast<const float4*>(&Wp[(size_t)(kc*64+r)*64 + c4]);
      *reinterpret_cast<float4*>(&sW[slot][r][c4]) = wv;
    }
  };

  if(K==64) stageA(0);

  #pragma unroll
  for(int ph=0; ph<4; ++ph){
    const bool dual = (ph<3);
    float accA[4][4]={}, accB[4][4]={};
    for(int kc=0; kc<K/64; ++kc){
      __syncthreads();                     // protect LDS restage from prior reads
      if(K==128) stageA(kc);
      stageW(Wl[2*ph], 0, kc);
      if(dual) stageW(Wl[2*ph+1], 1, kc);
      __syncthreads();
      #pragma unroll 4
      for(int k=0;k<64;++k){
        const float4 av = *reinterpret_cast<const float4*>(&sAT[k][tr*4]);
        const float4 wa = *reinterpret_cast<const float4*>(&sW[0][k][tc*4]);
        accA[0][0]+=av.x*wa.x; accA[0][1]+=av.x*wa.y; accA[0][2]+=av.x*wa.z; accA[0][3]+=av.x*wa.w;
        accA[1][0]+=av.y*wa.x; accA[1][1]+=av.y*wa.y; accA[1][2]+=av.y*wa.z; accA[1][3]+=av.y*wa.w;
        accA[2][0]+=av.z*wa.x; accA[2][1]+=av.z*wa.y; accA[2][2]+=av.z*wa.z; accA[2][3]+=av.z*wa.w;
        accA[3][0]+=av.w*wa.x; accA[3][1]+=av.w*wa.y; accA[3][2]+=av.w*wa.z; accA[3][3]+=av.w*wa.w;
        if(dual){
          const float4 wb = *reinterpret_cast<const float4*>(&sW[1][k][tc*4]);
          accB[0][0]+=av.x*wb.x; accB[0][1]+=av.x*wb.y; accB[0][2]+=av.x*wb.z; accB[0][3]+=av.x*wb.w;
          accB[1][0]+=av.y*wb.x; accB[1][1]+=av.y*wb.y; accB[1][2]+=av.y*wb.z; accB[1][3]+=av.y*wb.w;
          accB[2][0]+=av.z*wb.x; accB[2][1]+=av.z*wb.y; accB[2][2]+=av.z*wb.z; accB[2][3]+=av.z*wb.w;
          accB[3][0]+=av.w*wb.x; accB[3][1]+=av.w*wb.y; accB[3][2]+=av.w*wb.z; accB[3][3]+=av.w*wb.w;
        }
      }
    }
    #pragma unroll
    for(int i=0;i<4;++i){
      int m = m0 + tr*4 + i;
      if(m<M){
        #pragma unroll
        for(int j=0;j<4;++j){
          int c = tc*4+j;
          Ol[2*ph][(size_t)m*64+c] = f2b(accA[i][j]);
          if(dual){
            float vb = accB[i][j];
            if(ph==0) vb *= dis[m];       // P0s is the dis-scaled gather twin
            Ol[2*ph+1][(size_t)m*64+c] = f2b(vb);
          }
        }
      }
    }
  }
}

// mix GEMM: A = [h(64,bf16) | x(128,f32)] (M x 192), W = [Wmix0|Wmix1] (192 x (32+32))
// cols 0..31 -> Z0 (f32); cols 32..63 -> Z1s (bf16, PRE-SCALED by dis[m])
__global__ __launch_bounds__(256,2) void k_gemm_mix(const bf16* __restrict__ h, const float* __restrict__ x,
     const float* __restrict__ Wmix, float* __restrict__ Z0, bf16* __restrict__ Z1s,
     const float* __restrict__ dis, int M){
  __shared__ float sAT[64][68];
  __shared__ float sW[64][64];
  const int t=threadIdx.x, m0=blockIdx.x*64, tr=t>>4, tc=t&15;
  float acc[4][4]={};
  for(int kc=0;kc<3;++kc){
    #pragma unroll
    for(int it=0; it<4; ++it){
      int gli = t + it*256;
      int r = gli>>4, c4 = (gli&15)*4;
      int m = m0 + r;
      float v0=0,v1=0,v2=0,v3=0;
      if(m < M){
        if(kc==0){
          const bf16* hp=&h[(size_t)m*64 + c4];
          v0=b2f(hp[0]); v1=b2f(hp[1]); v2=b2f(hp[2]); v3=b2f(hp[3]);
        } else {
          float4 u = *reinterpret_cast<const float4*>(&x[(size_t)m*128 + (kc-1)*64 + c4]);
          v0=u.x; v1=u.y; v2=u.z; v3=u.w;
        }
      }
      sAT[c4+0][r]=v0; sAT[c4+1][r]=v1; sAT[c4+2][r]=v2; sAT[c4+3][r]=v3;
    }
    #pragma unroll
    for(int it=0; it<4; ++it){
      int gli = t + it*256;
      int r = gli>>4, c4 = (gli&15)*4;
      int gk = kc*64 + r;
      float4 wv = (c4<32) ? *reinterpret_cast<const float4*>(&Wmix[(size_t)gk*32 + c4])
                          : *reinterpret_cast<const float4*>(&Wmix[6144 + (size_t)gk*32 + (c4-32)]);
      *reinterpret_cast<float4*>(&sW[r][c4]) = wv;
    }
    __syncthreads();
    #pragma unroll 8
    for(int k=0;k<64;++k){
      const float4 av = *reinterpret_cast<const float4*>(&sAT[k][tr*4]);
      const float4 wv = *reinterpret_cast<const float4*>(&sW[k][tc*4]);
      acc[0][0]+=av.x*wv.x; acc[0][1]+=av.x*wv.y; acc[0][2]+=av.x*wv.z; acc[0][3]+=av.x*wv.w;
      acc[1][0]+=av.y*wv.x; acc[1][1]+=av.y*wv.y; acc[1][2]+=av.y*wv.z; acc[1][3]+=av.y*wv.w;
      acc[2][0]+=av.z*wv.x; acc[2][1]+=av.z*wv.y; acc[2][2]+=av.z*wv.z; acc[2][3]+=av.z*wv.w;
      acc[3][0]+=av.w*wv.x; acc[3][1]+=av.w*wv.y; acc[3][2]+=av.w*wv.z; acc[3][3]+=av.w*wv.w;
    }
    __syncthreads();
  }
  #pragma unroll
  for(int i=0;i<4;++i){
    int m=m0+tr*4+i;
    if(m<M){
      float dm = dis[m];
      #pragma unroll
      for(int j=0;j<4;++j){
        int c=tc*4+j;
        if(c<32) Z0[(size_t)m*32+c]=acc[i][j];
        else     Z1s[(size_t)m*32+(c-32)]=f2b(acc[i][j]*dm);
      }
    }
  }
}

// ---------------- sparse prop + Clenshaw combine ----------------
// a = dis[v] * sum_e BinS[src_e][f]   (BinS pre-scaled by dis[src]); L_hat t = -a
// Bsub recovered from its SCALED buffer: Bsub = BsubS[idx]*dinv[v]
// MODE 0: r = Z - 2a                         -> store SCALED (dis[v]*r)
// MODE 1: r = Z - 2a - BsubS*dinv            -> store SCALED
// MODE 2: r = relu(Z - a - BsubS*dinv + bias) + Zs + bias2 -> store normal bf16
// MODE 3: r = Z - a + bias                   -> store normal f32
template<int F, int MODE, typename ZT, typename OT>
__global__ __launch_bounds__(256) void k_prop(const int* __restrict__ row_ptr, const int* __restrict__ csr_src,
    const float* __restrict__ dis, const float* __restrict__ dinv, const bf16* __restrict__ BinS,
    const ZT* __restrict__ Z, const bf16* __restrict__ BsubS,
    const float* __restrict__ bias, const bf16* __restrict__ Zs, const float* __restrict__ bias2,
    OT* __restrict__ out, int N){
  constexpr int NPB = 256/F;
  int v = blockIdx.x*NPB + threadIdx.x/F;
  if(v>=N) return;
  int f = threadIdx.x % F;
  int e0=row_ptr[v], e1=row_ptr[v+1];
  float acc=0.f;
  int e=e0;
  for(; e+16<=e1; e+=16){
    int s[16];
    #pragma unroll
    for(int j=0;j<16;++j) s[j]=csr_src[e+j];
    float vv[16];
    #pragma unroll
    for(int j=0;j<16;++j) vv[j]=b2f(BinS[(unsigned)s[j]*F + f]);
    #pragma unroll
    for(int j=0;j<16;++j) acc+=vv[j];
  }
  if(e+8<=e1){
    int s[8];
    #pragma unroll
    for(int j=0;j<8;++j) s[j]=csr_src[e+j];
    float vv[8];
    #pragma unroll
    for(int j=0;j<8;++j) vv[j]=b2f(BinS[(unsigned)s[j]*F + f]);
    #pragma unroll
    for(int j=0;j<8;++j) acc+=vv[j];
    e+=8;
  }
  if(e<e1){
    #pragma unroll
    for(int j=0;j<8;++j){
      int idx=e+j;
      int s=csr_src[idx<e1 ? idx : e0];
      float vv=b2f(BinS[(unsigned)s*F + f]);
      acc += (idx<e1)? vv : 0.f;
    }
  }
  float dv = dis[v];
  float di = dinv[v];
  float a = dv*acc;
  unsigned idx=(unsigned)v*F+f;
  float r;
  if(MODE==0)      r = ldf(&Z[idx]) - 2.f*a;
  else if(MODE==1) r = ldf(&Z[idx]) - 2.f*a - b2f(BsubS[idx])*di;
  else if(MODE==2){ float tv = ldf(&Z[idx]) - a - b2f(BsubS[idx])*di + bias[f];
                    r = fmaxf(tv,0.f) + b2f(Zs[idx]) + bias2[f]; }
  else             r = ldf(&Z[idx]) - a + bias[f];
  if(MODE<=1) stf(&out[idx], dv*r);   // scaled store (single stream)
  else        stf(&out[idx], r);
}

// ---------------- host ----------------

extern "C" void kernel_launch(void* const* d_in, const int* in_sizes, int n_in,
                              void* d_out, int out_size, void* d_ws, size_t ws_size,
                              hipStream_t stream) {
  const int N = in_sizes[0]/128;     // 100000
  const int E = in_sizes[1]/2;       // 3200000

  const float* x    = (const float*)d_in[0];
  const int*   ei   = (const int*  )d_in[1];
  const float* W0   = (const float*)d_in[2];
  const float* b0   = (const float*)d_in[3];
  const float* Ws0  = (const float*)d_in[4];
  const float* bs0  = (const float*)d_in[5];
  const float* W1   = (const float*)d_in[6];
  const float* b1   = (const float*)d_in[7];
  const float* Ws1  = (const float*)d_in[8];
  const float* bs1  = (const float*)d_in[9];
  const float* W2   = (const float*)d_in[10];
  const float* b2   = (const float*)d_in[11];
  const float* Ws2  = (const float*)d_in[12];
  const float* bs2  = (const float*)d_in[13];
  const float* Wmix = (const float*)d_in[14];
  const float* bmix = (const float*)d_in[15];
  float* out = (float*)d_out;

  const int* src = ei;
  const int* dst = ei + E;

  // workspace carve (~155 MB, matches r7's proven footprint)
  size_t off=0;
  char* ws=(char*)d_ws;
  auto alloc=[&](size_t bytes)->void*{ void* p = ws+off; off=(off+bytes+255)&~(size_t)255; return p; };
  int*   csr_src = (int*)  alloc((size_t)E*4);
  int*   row_ptr = (int*)  alloc((size_t)(N+1)*4);
  int*   deg     = (int*)  alloc((size_t)N*4);
  float* dis     = (float*)alloc((size_t)N*4);
  float* dinv    = (float*)alloc((size_t)N*4);
  int*   bsums   = (int*)  alloc(2048);
  int*   boffs   = (int*)  alloc(2048);
  bf16*  Z0      = (bf16*) alloc((size_t)N*64*2);
  bf16*  Z1      = (bf16*) alloc((size_t)N*64*2);  // reused as f32 N*32 for mix Z0
  bf16*  Z2      = (bf16*) alloc((size_t)N*64*2);
  bf16*  Z3      = (bf16*) alloc((size_t)N*64*2);
  bf16*  Z4      = (bf16*) alloc((size_t)N*64*2);
  bf16*  Zsb     = (bf16*) alloc((size_t)N*64*2);
  bf16*  P0s     = (bf16*) alloc((size_t)N*64*2);
  bf16*  P1s     = (bf16*) alloc((size_t)N*64*2);
  bf16*  P2s     = (bf16*) alloc((size_t)N*64*2);
  bf16*  hA      = (bf16*) alloc((size_t)N*64*2);
  bf16*  hB      = (bf16*) alloc((size_t)N*64*2);
  if(off > ws_size){
    fprintf(stderr, "kernel_launch: workspace too small: need %zu, have %zu\n", off, ws_size);
    return;
  }

  const int NB   = (N+255)/256;
  const int gE   = (E+255)/256;
  const int gG   = (N+63)/64;
  const int gP64 = (N+3)/4;
  const int gP32 = (N+7)/8;

  // graph prep
  hipMemsetAsync(deg, 0, (size_t)N*4, stream);
  k_count<<<gE,256,0,stream>>>(dst, deg, E);
  k_scan1<<<NB,256,0,stream>>>(deg, row_ptr+1, bsums, N);
  k_scan2<<<1,512,0,stream>>>(bsums, boffs, NB);
  k_scan3<<<NB,256,0,stream>>>(row_ptr, boffs, deg, dis, dinv, N);
  k_fill<<<gE,256,0,stream>>>(src, dst, row_ptr, deg, csr_src, E);

  // per layer: ONE mega-GEMM (7 weights) then 5 back-to-back props (Clenshaw).
  auto PROPS=[&](const float* b, const float* bs_, bf16* hout){
    k_prop<64,0,bf16,bf16><<<gP64,256,0,stream>>>(row_ptr,csr_src,dis,dinv,P0s,Z4,nullptr,nullptr,nullptr,nullptr,P1s,N); // B4
    k_prop<64,1,bf16,bf16><<<gP64,256,0,stream>>>(row_ptr,csr_src,dis,dinv,P1s,Z3,P0s,nullptr,nullptr,nullptr,P2s,N);     // B3
    k_prop<64,1,bf16,bf16><<<gP64,256,0,stream>>>(row_ptr,csr_src,dis,dinv,P2s,Z2,P1s,nullptr,nullptr,nullptr,P0s,N);     // B2
    k_prop<64,1,bf16,bf16><<<gP64,256,0,stream>>>(row_ptr,csr_src,dis,dinv,P0s,Z1,P2s,nullptr,nullptr,nullptr,P1s,N);     // B1
    k_prop<64,2,bf16,bf16><<<gP64,256,0,stream>>>(row_ptr,csr_src,dis,dinv,P1s,Z0,P0s,b,Zsb,bs_,hout,N);                  // h'
  };

  {
    size_t WK=(size_t)128*64;
    k_gemm7<128,float><<<gG,256,0,stream>>>(x, Ws0, W0+5*WK, W0+4*WK, W0+3*WK, W0+2*WK, W0+1*WK, W0,
                                            Zsb, P0s, Z4, Z3, Z2, Z1, Z0, dis, N);
    PROPS(b0, bs0, hA);
  }
  {
    size_t WK=(size_t)64*64;
    k_gemm7<64,bf16><<<gG,256,0,stream>>>(hA, Ws1, W1+5*WK, W1+4*WK, W1+3*WK, W1+2*WK, W1+1*WK, W1,
                                          Zsb, P0s, Z4, Z3, Z2, Z1, Z0, dis, N);
    PROPS(b1, bs1, hB);
    k_gemm7<64,bf16><<<gG,256,0,stream>>>(hB, Ws2, W2+5*WK, W2+4*WK, W2+3*WK, W2+2*WK, W2+1*WK, W2,
                                          Zsb, P0s, Z4, Z3, Z2, Z1, Z0, dis, N);
    PROPS(b2, bs2, hA);
  }

  // mix head: out = Z0m + L_hat(Z1m) + bmix,  hcat = [hA | x]
  float* Zmixf = (float*)Z1;   // Z1 free after layer-2 props
  k_gemm_mix<<<gG,256,0,stream>>>(hA, x, Wmix, Zmixf, P0s, dis, N);
  k_prop<32,3,float,float><<<gP32,256,0,stream>>>(row_ptr,csr_src,dis,dinv,P0s,Zmixf,nullptr,bmix,nullptr,nullptr,out,N);
}